// Round 7
// baseline (823.183 us; speedup 1.0000x reference)
//
#include <hip/hip_runtime.h>
#include <stdint.h>

#define NB 64
#define NH 32
#define KCTX 4096
#define HID 7168
#define QLORA 1536
#define KVL 512
#define DTOT 576
#define NSPLIT 12
#define KSPAN 352
#define NTILE 22           // KSPAN/16
#define TK 16
#define SM_SCALE 0.07216878364870323f  // 1/sqrt(192)
#define NEGINF (-3.0e38f)

typedef __attribute__((ext_vector_type(4))) float f32x4;
typedef __attribute__((ext_vector_type(8))) __bf16 bf16x8;

#define LGKM_BARRIER() do{ asm volatile("s_waitcnt lgkmcnt(0)" ::: "memory"); __builtin_amdgcn_s_barrier(); } while(0)

static __device__ __forceinline__ unsigned short f2bf(float f){
    union{__bf16 h; unsigned short s;} x; x.h = (__bf16)f; return x.s;
}
static __device__ __forceinline__ float bf2f(unsigned short h){
    union{unsigned i;float f;}x; x.i=((unsigned)h)<<16; return x.f;
}
static __device__ __forceinline__ unsigned pack2(float a, float b){
    union{__bf16 h[2]; unsigned u;} x; x.h[0]=(__bf16)a; x.h[1]=(__bf16)b; return x.u;
}

// ---------- pack A[64][K] fp32 -> frag-ready bf16 hi/lo words: word idx = (k>>3)*64+m
__global__ __launch_bounds__(256) void pack_a(const float* __restrict__ A,
        unsigned short* __restrict__ Hi, unsigned short* __restrict__ Lo, int K)
{
    int idx = blockIdx.x*256 + threadIdx.x;
    int m = idx & 63, kb = idx >> 6;
    const float* src = A + (size_t)m*K + kb*8;
    float v[8];
    *(float4*)(v)   = *(const float4*)(src);
    *(float4*)(v+4) = *(const float4*)(src+4);
    unsigned short h[8], l[8];
#pragma unroll
    for (int j=0;j<8;++j){
        h[j] = f2bf(v[j]);
        l[j] = f2bf(v[j] - bf2f(h[j]));
    }
    uint4 uh, ul;
    uh.x=(unsigned)h[0]|((unsigned)h[1]<<16); uh.y=(unsigned)h[2]|((unsigned)h[3]<<16);
    uh.z=(unsigned)h[4]|((unsigned)h[5]<<16); uh.w=(unsigned)h[6]|((unsigned)h[7]<<16);
    ul.x=(unsigned)l[0]|((unsigned)l[1]<<16); ul.y=(unsigned)l[2]|((unsigned)l[3]<<16);
    ul.z=(unsigned)l[4]|((unsigned)l[5]<<16); ul.w=(unsigned)l[6]|((unsigned)l[7]<<16);
    *(uint4*)(Hi + (size_t)idx*8) = uh;
    *(uint4*)(Lo + (size_t)idx*8) = ul;
}

// ---------- MFMA skinny GEMM, double-buffered LDS, 1 barrier/step
__global__ __launch_bounds__(256) void gemm_mfma(
        const unsigned short* __restrict__ Ahi, const unsigned short* __restrict__ Alo,
        const float* __restrict__ Wm, float* __restrict__ P, int N, int ksteps)
{
    __shared__ unsigned short Ah[2][2048], Al[2][2048], Bh[2][2048], Bl[2][2048];
    const int tid = threadIdx.x;
    const int w = tid>>6, l = tid&63, lm = l&15, lg = l>>4;
    const int n0 = blockIdx.x*64;
    const int s  = blockIdx.y;
    const int mn = tid&63, ks = tid>>6;
    const int widx = ((mn>>4)*64 + ks*16 + (mn&15));

    f32x4 acc[4];
#pragma unroll
    for (int i=0;i<4;++i){ acc[i][0]=0.f; acc[i][1]=0.f; acc[i][2]=0.f; acc[i][3]=0.f; }

    uint4 ah4, al4; float wv[8];
    auto load_raw = [&](int t){
        const int k0 = (s*ksteps + t)*32;
        size_t gidx = (size_t)((k0>>3) + ks)*64 + mn;
        ah4 = *(const uint4*)(Ahi + gidx*8);
        al4 = *(const uint4*)(Alo + gidx*8);
        const float* wp = Wm + (size_t)(k0 + ks*8)*N + n0 + mn;
#pragma unroll
        for (int j=0;j<8;++j) wv[j] = wp[(size_t)j*N];
    };
    auto cvt_write = [&](int buf){
        unsigned short h[8], lo[8];
#pragma unroll
        for (int j=0;j<8;++j){
            h[j]  = f2bf(wv[j]);
            lo[j] = f2bf(wv[j] - bf2f(h[j]));
        }
        uint4 bh4, bl4;
        bh4.x=(unsigned)h[0]|((unsigned)h[1]<<16); bh4.y=(unsigned)h[2]|((unsigned)h[3]<<16);
        bh4.z=(unsigned)h[4]|((unsigned)h[5]<<16); bh4.w=(unsigned)h[6]|((unsigned)h[7]<<16);
        bl4.x=(unsigned)lo[0]|((unsigned)lo[1]<<16); bl4.y=(unsigned)lo[2]|((unsigned)lo[3]<<16);
        bl4.z=(unsigned)lo[4]|((unsigned)lo[5]<<16); bl4.w=(unsigned)lo[6]|((unsigned)lo[7]<<16);
        *(uint4*)(&Ah[buf][widx*8]) = ah4;
        *(uint4*)(&Al[buf][widx*8]) = al4;
        *(uint4*)(&Bh[buf][widx*8]) = bh4;
        *(uint4*)(&Bl[buf][widx*8]) = bl4;
    };

    load_raw(0);
    for (int t=0; t<ksteps; ++t){
        const int buf = t&1;
        cvt_write(buf);
        __syncthreads();
        if (t+1 < ksteps) load_raw(t+1);
        const int fa = (w*64 + lg*16 + lm)*8;
        bf16x8 fah = *(const bf16x8*)(&Ah[buf][fa]);
        bf16x8 fal = *(const bf16x8*)(&Al[buf][fa]);
#pragma unroll
        for (int nt=0;nt<4;++nt){
            const int fb = (nt*64 + lg*16 + lm)*8;
            bf16x8 fbh = *(const bf16x8*)(&Bh[buf][fb]);
            bf16x8 fbl = *(const bf16x8*)(&Bl[buf][fb]);
            acc[nt] = __builtin_amdgcn_mfma_f32_16x16x32_bf16(fah, fbh, acc[nt], 0,0,0);
            acc[nt] = __builtin_amdgcn_mfma_f32_16x16x32_bf16(fal, fbh, acc[nt], 0,0,0);
            acc[nt] = __builtin_amdgcn_mfma_f32_16x16x32_bf16(fah, fbl, acc[nt], 0,0,0);
        }
    }
#pragma unroll
    for (int nt=0;nt<4;++nt){
        int n = n0 + nt*16 + lm;
#pragma unroll
        for (int r=0;r<4;++r){
            int m = w*16 + lg*4 + r;
            P[((size_t)s*64 + m)*N + n] = acc[nt][r];
        }
    }
}

// ---------- reduce S partials + rmsnorm + pack hi/lo (A for w_q_b GEMM)
__global__ __launch_bounds__(256) void rms_qc_pack(const float* __restrict__ P,
        const float* __restrict__ w, unsigned short* __restrict__ Hi,
        unsigned short* __restrict__ Lo, int S)
{
    const int b = blockIdx.x, t = threadIdx.x;
    float v[6]; float ss = 0.f;
#pragma unroll
    for (int j=0;j<6;++j){
        int n = j*256 + t;
        float s = 0.f;
        for (int sp=0; sp<S; ++sp) s += P[((size_t)sp*64+b)*1536 + n];
        v[j] = s; ss += s*s;
    }
    __shared__ float red[4];
#pragma unroll
    for (int off=32; off>=1; off>>=1) ss += __shfl_xor(ss, off, 64);
    if ((t&63)==0) red[t>>6] = ss;
    __syncthreads();
    float tot = red[0]+red[1]+red[2]+red[3];
    float rs = rsqrtf(tot/1536.f + 1e-6f);
#pragma unroll
    for (int j=0;j<6;++j){
        int n = j*256+t;
        float val = v[j]*rs*w[n];
        unsigned short hs = f2bf(val);
        unsigned short ls = f2bf(val - bf2f(hs));
        size_t ui = (size_t)(n>>3)*512 + b*8 + (n&7);
        Hi[ui] = hs; Lo[ui] = ls;
    }
}

// ---------- generic partial reduce
__global__ __launch_bounds__(256) void reduce_sum(const float* __restrict__ P,
        float* __restrict__ out, int S, int N)
{
    int i = blockIdx.x*256 + threadIdx.x;
    int b = i / N, n = i - b*N;
    float s = 0.f;
    for (int sp=0; sp<S; ++sp) s += P[((size_t)sp*64+b)*N + n];
    out[i] = s;
}

// ---------- finish q: reduce partials; n<128 -> q fp32 (for qlnope A); rope -> query[512..]
__global__ __launch_bounds__(256) void finish_q(const float* __restrict__ P,
        const float* __restrict__ cosb, const float* __restrict__ sinb,
        float* __restrict__ q, float* __restrict__ query, int S)
{
    int i = blockIdx.x*256 + threadIdx.x;   // over 64*6144
    int b = i / 6144, n = i - b*6144;
    float s = 0.f;
    for (int sp=0; sp<S; ++sp) s += P[((size_t)sp*64+b)*6144 + n];
    int h = n/192, nl = n - h*192;
    if (nl < 128){
        q[((size_t)b*32+h)*192 + nl] = s;
    } else {
        int i2 = (nl-128)>>1;
        float other = __shfl_xor(s, 1);
        float c = cosb[b*32+i2], sn = sinb[b*32+i2];
        float* o = query + ((size_t)b*32+h)*576;
        if ((nl&1)==0) o[512+i2] = s*c - other*sn;
        else           o[544+i2] = s*c + other*sn;
    }
}

// ---------- reduce ckv partials + rmsnorm(512) + rope(last 64) -> latent[64][576]
__global__ __launch_bounds__(256) void reduce_kv_rope(const float* __restrict__ P,
        const float* __restrict__ w, const float* __restrict__ cosb, const float* __restrict__ sinb,
        float* __restrict__ latent, int S)
{
    const int b = blockIdx.x, t = threadIdx.x;
    __shared__ float vals[576];
    __shared__ float red[4];
    float ss = 0.f;
    for (int j=0;j<3;++j){
        int n = j*256+t;
        if (n < 576){
            float s=0.f;
            for (int sp=0;sp<S;++sp) s += P[((size_t)sp*64+b)*576 + n];
            vals[n]=s;
            if (n<512) ss += s*s;
        }
    }
#pragma unroll
    for (int off=32; off>=1; off>>=1) ss += __shfl_xor(ss, off, 64);
    if ((t&63)==0) red[t>>6]=ss;
    __syncthreads();
    float tot = red[0]+red[1]+red[2]+red[3];
    float rs = rsqrtf(tot/512.f + 1e-6f);
    for (int j=0;j<3;++j){
        int n = j*256+t;
        if (n<576){
            float o;
            if (n < 512) o = vals[n]*rs*w[n];
            else if (n < 544){ int i=n-512; o = vals[512+2*i]*cosb[b*32+i] - vals[513+2*i]*sinb[b*32+i]; }
            else            { int i=n-544; o = vals[513+2*i]*cosb[b*32+i] + vals[512+2*i]*sinb[b*32+i]; }
            latent[(size_t)b*576 + n] = o;
        }
    }
}

// ---------- ql_nope via MFMA: query[b][h][r] = sum_{k<128} q[b][h][k]*wukt[h][k][r]
// grid (32 h, 4 rblk); block 256 = 4 waves (wave = m-tile of b); N=128/block.
__global__ __launch_bounds__(256) void qlnope_mfma(const float* __restrict__ q,
        const float* __restrict__ wukt, float* __restrict__ query)
{
    __shared__ unsigned short Bh[4096], Bl[4096];
    const int h = blockIdx.x, r0 = blockIdx.y*128;
    const int tid = threadIdx.x;
    const int w = tid>>6, l = tid&63, lm = l&15, lg = l>>4;
    f32x4 acc[8];
#pragma unroll
    for (int i=0;i<8;++i){ acc[i][0]=0.f; acc[i][1]=0.f; acc[i][2]=0.f; acc[i][3]=0.f; }

    for (int ck=0; ck<4; ++ck){
        const int k0 = ck*32;
        // gather B into regs
        unsigned short hh[2][8], ll[2][8]; int wid0 = tid*2;
#pragma unroll
        for (int wi=0; wi<2; ++wi){
            int wid = wid0 + wi;
            int ntile = wid>>6, kg = (wid>>4)&3, nl = wid&15;
            int n = r0 + ntile*16 + nl;
            const float* wp = wukt + (size_t)h*65536 + (size_t)(k0+kg*8)*512 + n;
#pragma unroll
            for (int j=0;j<8;++j){
                float v = wp[(size_t)j*512];
                hh[wi][j] = f2bf(v);
                ll[wi][j] = f2bf(v - bf2f(hh[wi][j]));
            }
        }
        __syncthreads();
#pragma unroll
        for (int wi=0; wi<2; ++wi){
            int wid = wid0 + wi;
            uint4 uh, ul;
            uh.x=(unsigned)hh[wi][0]|((unsigned)hh[wi][1]<<16); uh.y=(unsigned)hh[wi][2]|((unsigned)hh[wi][3]<<16);
            uh.z=(unsigned)hh[wi][4]|((unsigned)hh[wi][5]<<16); uh.w=(unsigned)hh[wi][6]|((unsigned)hh[wi][7]<<16);
            ul.x=(unsigned)ll[wi][0]|((unsigned)ll[wi][1]<<16); ul.y=(unsigned)ll[wi][2]|((unsigned)ll[wi][3]<<16);
            ul.z=(unsigned)ll[wi][4]|((unsigned)ll[wi][5]<<16); ul.w=(unsigned)ll[wi][6]|((unsigned)ll[wi][7]<<16);
            *(uint4*)(Bh + wid*8) = uh;
            *(uint4*)(Bl + wid*8) = ul;
        }
        __syncthreads();
        // A frag from global fp32
        const int bb = w*16 + lm;
        const float* ap = q + ((size_t)bb*32 + h)*192 + k0 + lg*8;
        float4 a0 = *(const float4*)ap;
        float4 a1 = *(const float4*)(ap+4);
        union{uint4 u; bf16x8 v;} fh, fl;
        fh.u.x=pack2(a0.x,a0.y); fh.u.y=pack2(a0.z,a0.w);
        fh.u.z=pack2(a1.x,a1.y); fh.u.w=pack2(a1.z,a1.w);
        float r0f=a0.x-bf2f(f2bf(a0.x)), r1f=a0.y-bf2f(f2bf(a0.y));
        float r2f=a0.z-bf2f(f2bf(a0.z)), r3f=a0.w-bf2f(f2bf(a0.w));
        float r4f=a1.x-bf2f(f2bf(a1.x)), r5f=a1.y-bf2f(f2bf(a1.y));
        float r6f=a1.z-bf2f(f2bf(a1.z)), r7f=a1.w-bf2f(f2bf(a1.w));
        fl.u.x=pack2(r0f,r1f); fl.u.y=pack2(r2f,r3f);
        fl.u.z=pack2(r4f,r5f); fl.u.w=pack2(r6f,r7f);
#pragma unroll
        for (int nt=0;nt<8;++nt){
            const int fb = (nt*64 + lg*16 + lm)*8;
            bf16x8 fbh = *(const bf16x8*)(Bh + fb);
            bf16x8 fbl = *(const bf16x8*)(Bl + fb);
            acc[nt] = __builtin_amdgcn_mfma_f32_16x16x32_bf16(fh.v, fbh, acc[nt], 0,0,0);
            acc[nt] = __builtin_amdgcn_mfma_f32_16x16x32_bf16(fl.v, fbh, acc[nt], 0,0,0);
            acc[nt] = __builtin_amdgcn_mfma_f32_16x16x32_bf16(fh.v, fbl, acc[nt], 0,0,0);
        }
        __syncthreads();
    }
#pragma unroll
    for (int nt=0;nt<8;++nt){
        int r = r0 + nt*16 + lm;
#pragma unroll
        for (int qq=0;qq<4;++qq){
            int bb = w*16 + lg*4 + qq;
            query[((size_t)bb*32 + h)*576 + r] = acc[nt][qq];
        }
    }
}

// Vt flat layout: addr_u16(d,key) = (d>>2)*64 + ((d&3)^((d>>3)&3))*16 + key
static __device__ __forceinline__ int vt_addr(int d, int key){
    return (d>>2)*64 + (((d&3)^((d>>3)&3))<<4) + key;
}

// ---------- flash decode attention v4: split issue/commit staging, raw barriers, setprio
__global__ __launch_bounds__(256,3) void attn_mfma(const float* __restrict__ query,
        const float* __restrict__ kv, const float* __restrict__ latent,
        const int* __restrict__ slots, const int* __restrict__ seq_lens,
        float* __restrict__ Opart, float* __restrict__ Mpart, float* __restrict__ Lpart)
{
    __shared__ unsigned short Krows[TK*576];
    __shared__ unsigned short Vt[8192];
    __shared__ float S_s[2][32][16];
    __shared__ unsigned short P_s[32][40];
    __shared__ float alpha_s[32];

    const int b = blockIdx.y, sp = blockIdx.x;
    const int tid = threadIdx.x;
    const int w = tid>>6, l = tid&63;
    const int lm = l&15, lg = l>>4;
    const int ht = w&1;
    const int dh = w>>1;
    const int seqlen = seq_lens[b];
    const int slot = slots[b];
    const int k0 = sp*KSPAN;
    const int myh = tid>>3, s5 = tid&7;

    {
        int id = tid*2;
        P_s[id>>4][16 + (id&15)] = 0;
        id++;
        P_s[id>>4][16 + (id&15)] = 0;
    }

    bf16x8 qf[9];
    {
        const float* qrow = query + ((size_t)b*32 + ht*16 + lm)*576;
#pragma unroll
        for (int ss=0;ss<9;++ss){
            int d0 = (dh*9+ss)*32 + lg*8;
            float4 a = *(const float4*)(qrow + d0);
            float4 c = *(const float4*)(qrow + d0 + 4);
            union{uint4 u; bf16x8 v;} cv;
            cv.u.x=pack2(a.x,a.y); cv.u.y=pack2(a.z,a.w);
            cv.u.z=pack2(c.x,c.y); cv.u.w=pack2(c.z,c.w);
            qf[ss]=cv.v;
        }
    }

    float4 pld[9];
    auto stage_issue = [&](int tt){
#pragma unroll
        for (int c=0;c<9;++c){
            int idx = c*256 + tid;
            int row = idx/144, col = (idx - row*144)*4;
            int gk = k0 + tt*TK + row;
            if (gk > KCTX-1) gk = KCTX-1;
            const float* src = (gk==slot) ? (latent + (size_t)b*576 + col)
                                          : (kv + ((size_t)b*KCTX + gk)*576 + col);
            pld[c] = *(const float4*)src;
        }
    };
    auto stage_commit = [&](){
#pragma unroll
        for (int c=0;c<9;++c){
            int idx = c*256 + tid;
            int row = idx/144, col = (idx - row*144)*4;
            unsigned lo_ = pack2(pld[c].x, pld[c].y);
            unsigned hi_ = pack2(pld[c].z, pld[c].w);
            uint2 u; u.x=lo_; u.y=hi_;
            *(uint2*)(Krows + row*576 + (col ^ ((row&7)<<3))) = u;
        }
    };

    f32x4 oacc[16];
#pragma unroll
    for (int i=0;i<16;++i){ oacc[i][0]=0.f; oacc[i][1]=0.f; oacc[i][2]=0.f; oacc[i][3]=0.f; }
    float m_run = NEGINF, l_run = 0.f;

    stage_issue(0); stage_commit();
    LGKM_BARRIER();

    for (int tt=0; tt<NTILE; ++tt){
        const bool more = (tt+1 < NTILE);
        if (more) stage_issue(tt+1);      // loads stay in flight across raw barriers

        // ---- transpose Krows(d<512) -> Vt
        {
            const int kg = tid&1;
            const int d0 = (tid>>1)*4;
            uint2 rw[8];
#pragma unroll
            for (int i=0;i<8;++i){
                int row = kg*8 + i;
                rw[i] = *(const uint2*)(Krows + row*576 + (d0 ^ ((row&7)<<3)));
            }
#pragma unroll
            for (int j=0;j<4;++j){
                const int sel = j>>1, sh = (j&1)*16;
                unsigned e0 = ((sel? rw[0].y : rw[0].x) >> sh) & 0xffffu;
                unsigned e1 = ((sel? rw[1].y : rw[1].x) >> sh) & 0xffffu;
                unsigned e2 = ((sel? rw[2].y : rw[2].x) >> sh) & 0xffffu;
                unsigned e3 = ((sel? rw[3].y : rw[3].x) >> sh) & 0xffffu;
                unsigned e4 = ((sel? rw[4].y : rw[4].x) >> sh) & 0xffffu;
                unsigned e5 = ((sel? rw[5].y : rw[5].x) >> sh) & 0xffffu;
                unsigned e6 = ((sel? rw[6].y : rw[6].x) >> sh) & 0xffffu;
                unsigned e7 = ((sel? rw[7].y : rw[7].x) >> sh) & 0xffffu;
                uint4 o;
                o.x = e0 | (e1<<16); o.y = e2 | (e3<<16);
                o.z = e4 | (e5<<16); o.w = e6 | (e7<<16);
                *(uint4*)(Vt + vt_addr(d0+j, kg*8)) = o;
            }
        }
        // ---- QK^T partial
        {
            f32x4 sacc; sacc[0]=0.f; sacc[1]=0.f; sacc[2]=0.f; sacc[3]=0.f;
            const unsigned short* kb = Krows + lm*576;
            const int sw = (lm&7)<<3;
            __builtin_amdgcn_s_setprio(1);
#pragma unroll
            for (int ss=0;ss<9;++ss){
                int dof = (dh*9+ss)*32 + lg*8;
                bf16x8 bv = *(const bf16x8*)(kb + (dof ^ sw));
                sacc = __builtin_amdgcn_mfma_f32_16x16x32_bf16(qf[ss], bv, sacc, 0,0,0);
            }
            __builtin_amdgcn_s_setprio(0);
#pragma unroll
            for (int r=0;r<4;++r) S_s[dh][ht*16 + (lg<<2) + r][lm] = sacc[r];
        }
        LGKM_BARRIER();                    // #1 (vmcnt NOT drained)

        // ---- online softmax
        {
            const int kbase = k0 + tt*TK;
            float sc[2];
#pragma unroll
            for (int j=0;j<2;++j){
                int k = s5 + 8*j;
                float v = (S_s[0][myh][k] + S_s[1][myh][k])*SM_SCALE;
                sc[j] = (kbase + k < seqlen) ? v : NEGINF;
            }
            float tmax = fmaxf(sc[0],sc[1]);
            tmax = fmaxf(tmax, __shfl_xor(tmax,1));
            tmax = fmaxf(tmax, __shfl_xor(tmax,2));
            tmax = fmaxf(tmax, __shfl_xor(tmax,4));
            float mnew = fmaxf(m_run, tmax);
            float al = __expf(m_run - mnew);
            float ps = 0.f;
#pragma unroll
            for (int j=0;j<2;++j){
                float pv = (sc[j] > 0.5f*NEGINF) ? __expf(sc[j]-mnew) : 0.f;
                ps += pv;
                P_s[myh][s5 + 8*j] = f2bf(pv);
            }
            ps += __shfl_xor(ps,1); ps += __shfl_xor(ps,2); ps += __shfl_xor(ps,4);
            l_run = l_run*al + ps;
            m_run = mnew;
            if (s5==0) alpha_s[myh] = al;
        }
        LGKM_BARRIER();                    // #2

        if (more) stage_commit();          // vmcnt waited here (auto), Krows(t) readers all done

        // ---- PV
        {
            float al4[4];
#pragma unroll
            for (int r=0;r<4;++r) al4[r] = alpha_s[ht*16 + (lg<<2) + r];
            bf16x8 pa = *(const bf16x8*)(&P_s[ht*16+lm][lg*8]);
            __builtin_amdgcn_s_setprio(1);
#pragma unroll
            for (int nt=0;nt<16;++nt){
                f32x4 o = oacc[nt];
                o[0]*=al4[0]; o[1]*=al4[1]; o[2]*=al4[2]; o[3]*=al4[3];
                int r = dh*256 + nt*16 + lm;
                bf16x8 bv = *(const bf16x8*)(Vt + vt_addr(r, (lg&1)*8));
                oacc[nt] = __builtin_amdgcn_mfma_f32_16x16x32_bf16(pa, bv, o, 0,0,0);
            }
            __builtin_amdgcn_s_setprio(0);
        }
        LGKM_BARRIER();                    // #3
    }

    const int obase = (b*NSPLIT+sp)*32;
#pragma unroll
    for (int nt=0;nt<16;++nt){
        int r = dh*256 + nt*16 + lm;
#pragma unroll
        for (int qq=0;qq<4;++qq){
            int h = ht*16 + (lg<<2) + qq;
            Opart[((size_t)(obase+h))*512 + r] = oacc[nt][qq];
        }
    }
    if (s5==0){ Mpart[obase+myh]=m_run; Lpart[obase+myh]=l_run; }
}

// ---------- merge NSPLIT flash partials -> attn[b][h][512]
__global__ __launch_bounds__(256) void merge_attn(const float* __restrict__ Opart,
        const float* __restrict__ Mpart, const float* __restrict__ Lpart, float* __restrict__ attn)
{
    const int bh = blockIdx.x;
    const int b = bh>>5, h = bh&31;
    const int t = threadIdx.x;
    float m[NSPLIT], lw[NSPLIT];
    float M = NEGINF;
#pragma unroll
    for (int s=0;s<NSPLIT;++s){ m[s] = Mpart[(b*NSPLIT+s)*32 + h]; M = fmaxf(M,m[s]); }
    float L = 0.f;
#pragma unroll
    for (int s=0;s<NSPLIT;++s){ lw[s] = __expf(m[s]-M); L += lw[s]*Lpart[(b*NSPLIT+s)*32+h]; }
    float inv = 1.f/L;
#pragma unroll
    for (int j=0;j<2;++j){
        int r = j*256+t;
        float o = 0.f;
#pragma unroll
        for (int s=0;s<NSPLIT;++s)
            o += lw[s]*Opart[((size_t)((b*NSPLIT+s)*32) + h)*512 + r];
        attn[((size_t)b*32+h)*512 + r] = o*inv;
    }
}

// ---------- av_uv via MFMA + fused hi/lo pack of ao (A for w_o GEMM)
// grid 32 (h); block 256 = 4 waves; per h: C[64 b][128 v], K=512 in 16 chunks.
__global__ __launch_bounds__(256) void av_uv_mfma(const float* __restrict__ attn,
        const float* __restrict__ wuv,
        unsigned short* __restrict__ Hi, unsigned short* __restrict__ Lo)
{
    __shared__ unsigned short Bh[4096], Bl[4096];
    const int h = blockIdx.x;
    const int tid = threadIdx.x;
    const int w = tid>>6, l = tid&63, lm = l&15, lg = l>>4;
    f32x4 acc[8];
#pragma unroll
    for (int i=0;i<8;++i){ acc[i][0]=0.f; acc[i][1]=0.f; acc[i][2]=0.f; acc[i][3]=0.f; }

    for (int ck=0; ck<16; ++ck){
        const int k0 = ck*32;
        unsigned short hh[2][8], ll[2][8]; int wid0 = tid*2;
#pragma unroll
        for (int wi=0; wi<2; ++wi){
            int wid = wid0 + wi;
            int ntile = wid>>6, kg = (wid>>4)&3, nl = wid&15;
            int n = ntile*16 + nl;
            const float* wp = wuv + (size_t)h*65536 + (size_t)(k0+kg*8)*128 + n;
#pragma unroll
            for (int j=0;j<8;++j){
                float v = wp[(size_t)j*128];
                hh[wi][j] = f2bf(v);
                ll[wi][j] = f2bf(v - bf2f(hh[wi][j]));
            }
        }
        __syncthreads();
#pragma unroll
        for (int wi=0; wi<2; ++wi){
            int wid = wid0 + wi;
            uint4 uh, ul;
            uh.x=(unsigned)hh[wi][0]|((unsigned)hh[wi][1]<<16); uh.y=(unsigned)hh[wi][2]|((unsigned)hh[wi][3]<<16);
            uh.z=(unsigned)hh[wi][4]|((unsigned)hh[wi][5]<<16); uh.w=(unsigned)hh[wi][6]|((unsigned)hh[wi][7]<<16);
            ul.x=(unsigned)ll[wi][0]|((unsigned)ll[wi][1]<<16); ul.y=(unsigned)ll[wi][2]|((unsigned)ll[wi][3]<<16);
            ul.z=(unsigned)ll[wi][4]|((unsigned)ll[wi][5]<<16); ul.w=(unsigned)ll[wi][6]|((unsigned)ll[wi][7]<<16);
            *(uint4*)(Bh + wid*8) = uh;
            *(uint4*)(Bl + wid*8) = ul;
        }
        __syncthreads();
        const int bb = w*16 + lm;
        const float* ap = attn + ((size_t)bb*32 + h)*512 + k0 + lg*8;
        float4 a0 = *(const float4*)ap;
        float4 a1 = *(const float4*)(ap+4);
        union{uint4 u; bf16x8 v;} fh, fl;
        fh.u.x=pack2(a0.x,a0.y); fh.u.y=pack2(a0.z,a0.w);
        fh.u.z=pack2(a1.x,a1.y); fh.u.w=pack2(a1.z,a1.w);
        float r0f=a0.x-bf2f(f2bf(a0.x)), r1f=a0.y-bf2f(f2bf(a0.y));
        float r2f=a0.z-bf2f(f2bf(a0.z)), r3f=a0.w-bf2f(f2bf(a0.w));
        float r4f=a1.x-bf2f(f2bf(a1.x)), r5f=a1.y-bf2f(f2bf(a1.y));
        float r6f=a1.z-bf2f(f2bf(a1.z)), r7f=a1.w-bf2f(f2bf(a1.w));
        fl.u.x=pack2(r0f,r1f); fl.u.y=pack2(r2f,r3f);
        fl.u.z=pack2(r4f,r5f); fl.u.w=pack2(r6f,r7f);
#pragma unroll
        for (int nt=0;nt<8;++nt){
            const int fb = (nt*64 + lg*16 + lm)*8;
            bf16x8 fbh = *(const bf16x8*)(Bh + fb);
            bf16x8 fbl = *(const bf16x8*)(Bl + fb);
            acc[nt] = __builtin_amdgcn_mfma_f32_16x16x32_bf16(fh.v, fbh, acc[nt], 0,0,0);
            acc[nt] = __builtin_amdgcn_mfma_f32_16x16x32_bf16(fl.v, fbh, acc[nt], 0,0,0);
            acc[nt] = __builtin_amdgcn_mfma_f32_16x16x32_bf16(fh.v, fbl, acc[nt], 0,0,0);
        }
        __syncthreads();
    }
    // epilogue: pack ao[b][h*128+v] as hi/lo words (k>>3)*64+m
#pragma unroll
    for (int nt=0;nt<8;++nt){
#pragma unroll
        for (int qq=0;qq<4;++qq){
            float val = acc[nt][qq];
            int bb = w*16 + lg*4 + qq;
            int k = h*128 + nt*16 + lm;
            unsigned short hv = f2bf(val);
            unsigned short lv = f2bf(val - bf2f(hv));
            size_t ui = (size_t)(k>>3)*512 + bb*8 + (k&7);
            Hi[ui] = hv; Lo[ui] = lv;
        }
    }
}

extern "C" void kernel_launch(void* const* d_in, const int* in_sizes, int n_in,
                              void* d_out, int out_size, void* d_ws, size_t ws_size,
                              hipStream_t stream)
{
    const float* hidden = (const float*)d_in[0];
    const float* cosb   = (const float*)d_in[1];
    const float* sinb   = (const float*)d_in[2];
    const float* kv     = (const float*)d_in[3];
    const float* w_q_a  = (const float*)d_in[4];
    const float* q_ln   = (const float*)d_in[5];
    const float* w_q_b  = (const float*)d_in[6];
    const float* w_kv_a = (const float*)d_in[7];
    const float* kv_ln  = (const float*)d_in[8];
    const float* w_uk_t = (const float*)d_in[9];
    const float* w_uv   = (const float*)d_in[10];
    const float* w_o    = (const float*)d_in[11];
    const int* slots    = (const int*)d_in[12];
    const int* seqlens  = (const int*)d_in[13];
    float* out = (float*)d_out;

    float* W = (float*)d_ws;
    float* P      = W;                   // 12,582,912 f32 (gemm partials / attn Opart)
    float* q      = W + 12582912;        // 393,216
    float* latent = W + 12976128;        // 36,864
    float* query  = W + 13012992;        // 1,179,648
    float* Mp     = W + 14192640;        // 24,576
    float* Lp     = W + 14217216;        // 24,576
    float* attn   = W + 14241792;        // 1,048,576
    unsigned short* pkhid_h = (unsigned short*)(W + 15290368);  // 229,376 f32 each
    unsigned short* pkhid_l = (unsigned short*)(W + 15519744);
    unsigned short* pkqc_h  = (unsigned short*)(W + 15749120);  // 49,152 f32 each
    unsigned short* pkqc_l  = (unsigned short*)(W + 15798272);
    unsigned short* pkao_h  = (unsigned short*)(W + 15847424);  // 131,072 f32 each
    unsigned short* pkao_l  = (unsigned short*)(W + 15978496);  // end 16,109,568

    // q branch
    hipLaunchKernelGGL(pack_a, dim3(224), dim3(256), 0, stream, hidden, pkhid_h, pkhid_l, 7168);
    hipLaunchKernelGGL(gemm_mfma, dim3(24,28), dim3(256), 0, stream, pkhid_h, pkhid_l, w_q_a, P, 1536, 8);
    hipLaunchKernelGGL(rms_qc_pack, dim3(64), dim3(256), 0, stream, P, q_ln, pkqc_h, pkqc_l, 28);
    hipLaunchKernelGGL(gemm_mfma, dim3(96,6), dim3(256), 0, stream, pkqc_h, pkqc_l, w_q_b, P, 6144, 8);
    hipLaunchKernelGGL(finish_q, dim3(1536), dim3(256), 0, stream, P, cosb, sinb, q, query, 6);
    // kv branch
    hipLaunchKernelGGL(gemm_mfma, dim3(9,56), dim3(256), 0, stream, pkhid_h, pkhid_l, w_kv_a, P, 576, 4);
    hipLaunchKernelGGL(reduce_kv_rope, dim3(64), dim3(256), 0, stream, P, kv_ln, cosb, sinb, latent, 56);
    // query nope
    hipLaunchKernelGGL(qlnope_mfma, dim3(32,4), dim3(256), 0, stream, q, w_uk_t, query);
    // attention
    hipLaunchKernelGGL(attn_mfma, dim3(NSPLIT,64), dim3(256), 0, stream,
                       query, kv, latent, slots, seqlens, P, Mp, Lp);
    hipLaunchKernelGGL(merge_attn, dim3(2048), dim3(256), 0, stream, P, Mp, Lp, attn);
    hipLaunchKernelGGL(av_uv_mfma, dim3(32), dim3(256), 0, stream, attn, w_uv, pkao_h, pkao_l);
    // output projection
    hipLaunchKernelGGL(gemm_mfma, dim3(112,8), dim3(256), 0, stream, pkao_h, pkao_l, w_o, P, 7168, 16);
    hipLaunchKernelGGL(reduce_sum, dim3(1792), dim3(256), 0, stream, P, out, 8, 7168);
}

// Round 8
// 430.143 us; speedup vs baseline: 1.9137x; 1.9137x over previous
//
#include <hip/hip_runtime.h>
#include <stdint.h>

#define NB 64
#define NH 32
#define KCTX 4096
#define HID 7168
#define QLORA 1536
#define KVL 512
#define DTOT 576
#define NSPLIT 4
#define KSPAN 1024
#define NTILE 64           // KSPAN/16
#define TK 16
#define SM_SCALE 0.07216878364870323f  // 1/sqrt(192)
#define NEGINF (-3.0e38f)

typedef __attribute__((ext_vector_type(4))) float f32x4;
typedef __attribute__((ext_vector_type(8))) __bf16 bf16x8;

#define LGKM_BARRIER() do{ asm volatile("s_waitcnt lgkmcnt(0)" ::: "memory"); __builtin_amdgcn_s_barrier(); } while(0)
#define VM_BARRIER()   do{ asm volatile("s_waitcnt vmcnt(0)"   ::: "memory"); __builtin_amdgcn_s_barrier(); } while(0)

static __device__ __forceinline__ void glds16(const void* g, void* s){
    __builtin_amdgcn_global_load_lds((const __attribute__((address_space(1))) void*)g,
                                     (__attribute__((address_space(3))) void*)s, 16, 0, 0);
}

static __device__ __forceinline__ unsigned short f2bf(float f){
    union{__bf16 h; unsigned short s;} x; x.h = (__bf16)f; return x.s;
}
static __device__ __forceinline__ float bf2f(unsigned short h){
    union{unsigned i;float f;}x; x.i=((unsigned)h)<<16; return x.f;
}
static __device__ __forceinline__ unsigned pack2(float a, float b){
    union{__bf16 h[2]; unsigned u;} x; x.h[0]=(__bf16)a; x.h[1]=(__bf16)b; return x.u;
}

// ---------- pack A[64][K] fp32 -> frag-ready bf16 hi/lo words: word idx = (k>>3)*64+m
__global__ __launch_bounds__(256) void pack_a(const float* __restrict__ A,
        unsigned short* __restrict__ Hi, unsigned short* __restrict__ Lo, int K)
{
    int idx = blockIdx.x*256 + threadIdx.x;
    int m = idx & 63, kb = idx >> 6;
    const float* src = A + (size_t)m*K + kb*8;
    float v[8];
    *(float4*)(v)   = *(const float4*)(src);
    *(float4*)(v+4) = *(const float4*)(src+4);
    unsigned short h[8], l[8];
#pragma unroll
    for (int j=0;j<8;++j){
        h[j] = f2bf(v[j]);
        l[j] = f2bf(v[j] - bf2f(h[j]));
    }
    uint4 uh, ul;
    uh.x=(unsigned)h[0]|((unsigned)h[1]<<16); uh.y=(unsigned)h[2]|((unsigned)h[3]<<16);
    uh.z=(unsigned)h[4]|((unsigned)h[5]<<16); uh.w=(unsigned)h[6]|((unsigned)h[7]<<16);
    ul.x=(unsigned)l[0]|((unsigned)l[1]<<16); ul.y=(unsigned)l[2]|((unsigned)l[3]<<16);
    ul.z=(unsigned)l[4]|((unsigned)l[5]<<16); ul.w=(unsigned)l[6]|((unsigned)l[7]<<16);
    *(uint4*)(Hi + (size_t)idx*8) = uh;
    *(uint4*)(Lo + (size_t)idx*8) = ul;
}

// ---------- MFMA skinny GEMM, double-buffered LDS, 1 barrier/step
__global__ __launch_bounds__(256) void gemm_mfma(
        const unsigned short* __restrict__ Ahi, const unsigned short* __restrict__ Alo,
        const float* __restrict__ Wm, float* __restrict__ P, int N, int ksteps)
{
    __shared__ unsigned short Ah[2][2048], Al[2][2048], Bh[2][2048], Bl[2][2048];
    const int tid = threadIdx.x;
    const int w = tid>>6, l = tid&63, lm = l&15, lg = l>>4;
    const int n0 = blockIdx.x*64;
    const int s  = blockIdx.y;
    const int mn = tid&63, ks = tid>>6;
    const int widx = ((mn>>4)*64 + ks*16 + (mn&15));

    f32x4 acc[4];
#pragma unroll
    for (int i=0;i<4;++i){ acc[i][0]=0.f; acc[i][1]=0.f; acc[i][2]=0.f; acc[i][3]=0.f; }

    uint4 ah4, al4; float wv[8];
    auto load_raw = [&](int t){
        const int k0 = (s*ksteps + t)*32;
        size_t gidx = (size_t)((k0>>3) + ks)*64 + mn;
        ah4 = *(const uint4*)(Ahi + gidx*8);
        al4 = *(const uint4*)(Alo + gidx*8);
        const float* wp = Wm + (size_t)(k0 + ks*8)*N + n0 + mn;
#pragma unroll
        for (int j=0;j<8;++j) wv[j] = wp[(size_t)j*N];
    };
    auto cvt_write = [&](int buf){
        unsigned short h[8], lo[8];
#pragma unroll
        for (int j=0;j<8;++j){
            h[j]  = f2bf(wv[j]);
            lo[j] = f2bf(wv[j] - bf2f(h[j]));
        }
        uint4 bh4, bl4;
        bh4.x=(unsigned)h[0]|((unsigned)h[1]<<16); bh4.y=(unsigned)h[2]|((unsigned)h[3]<<16);
        bh4.z=(unsigned)h[4]|((unsigned)h[5]<<16); bh4.w=(unsigned)h[6]|((unsigned)h[7]<<16);
        bl4.x=(unsigned)lo[0]|((unsigned)lo[1]<<16); bl4.y=(unsigned)lo[2]|((unsigned)lo[3]<<16);
        bl4.z=(unsigned)lo[4]|((unsigned)lo[5]<<16); bl4.w=(unsigned)lo[6]|((unsigned)lo[7]<<16);
        *(uint4*)(&Ah[buf][widx*8]) = ah4;
        *(uint4*)(&Al[buf][widx*8]) = al4;
        *(uint4*)(&Bh[buf][widx*8]) = bh4;
        *(uint4*)(&Bl[buf][widx*8]) = bl4;
    };

    load_raw(0);
    for (int t=0; t<ksteps; ++t){
        const int buf = t&1;
        cvt_write(buf);
        __syncthreads();
        if (t+1 < ksteps) load_raw(t+1);
        const int fa = (w*64 + lg*16 + lm)*8;
        bf16x8 fah = *(const bf16x8*)(&Ah[buf][fa]);
        bf16x8 fal = *(const bf16x8*)(&Al[buf][fa]);
#pragma unroll
        for (int nt=0;nt<4;++nt){
            const int fb = (nt*64 + lg*16 + lm)*8;
            bf16x8 fbh = *(const bf16x8*)(&Bh[buf][fb]);
            bf16x8 fbl = *(const bf16x8*)(&Bl[buf][fb]);
            acc[nt] = __builtin_amdgcn_mfma_f32_16x16x32_bf16(fah, fbh, acc[nt], 0,0,0);
            acc[nt] = __builtin_amdgcn_mfma_f32_16x16x32_bf16(fal, fbh, acc[nt], 0,0,0);
            acc[nt] = __builtin_amdgcn_mfma_f32_16x16x32_bf16(fah, fbl, acc[nt], 0,0,0);
        }
    }
#pragma unroll
    for (int nt=0;nt<4;++nt){
        int n = n0 + nt*16 + lm;
#pragma unroll
        for (int r=0;r<4;++r){
            int m = w*16 + lg*4 + r;
            P[((size_t)s*64 + m)*N + n] = acc[nt][r];
        }
    }
}

// ---------- reduce S partials + rmsnorm + pack hi/lo (A for w_q_b GEMM)
__global__ __launch_bounds__(256) void rms_qc_pack(const float* __restrict__ P,
        const float* __restrict__ w, unsigned short* __restrict__ Hi,
        unsigned short* __restrict__ Lo, int S)
{
    const int b = blockIdx.x, t = threadIdx.x;
    float v[6]; float ss = 0.f;
#pragma unroll
    for (int j=0;j<6;++j){
        int n = j*256 + t;
        float s = 0.f;
        for (int sp=0; sp<S; ++sp) s += P[((size_t)sp*64+b)*1536 + n];
        v[j] = s; ss += s*s;
    }
    __shared__ float red[4];
#pragma unroll
    for (int off=32; off>=1; off>>=1) ss += __shfl_xor(ss, off, 64);
    if ((t&63)==0) red[t>>6] = ss;
    __syncthreads();
    float tot = red[0]+red[1]+red[2]+red[3];
    float rs = rsqrtf(tot/1536.f + 1e-6f);
#pragma unroll
    for (int j=0;j<6;++j){
        int n = j*256+t;
        float val = v[j]*rs*w[n];
        unsigned short hs = f2bf(val);
        unsigned short ls = f2bf(val - bf2f(hs));
        size_t ui = (size_t)(n>>3)*512 + b*8 + (n&7);
        Hi[ui] = hs; Lo[ui] = ls;
    }
}

// ---------- generic partial reduce
__global__ __launch_bounds__(256) void reduce_sum(const float* __restrict__ P,
        float* __restrict__ out, int S, int N)
{
    int i = blockIdx.x*256 + threadIdx.x;
    int b = i / N, n = i - b*N;
    float s = 0.f;
    for (int sp=0; sp<S; ++sp) s += P[((size_t)sp*64+b)*N + n];
    out[i] = s;
}

// ---------- finish q: reduce partials; n<128 -> q fp32 (for qlnope A); rope -> query[512..]
__global__ __launch_bounds__(256) void finish_q(const float* __restrict__ P,
        const float* __restrict__ cosb, const float* __restrict__ sinb,
        float* __restrict__ q, float* __restrict__ query, int S)
{
    int i = blockIdx.x*256 + threadIdx.x;   // over 64*6144
    int b = i / 6144, n = i - b*6144;
    float s = 0.f;
    for (int sp=0; sp<S; ++sp) s += P[((size_t)sp*64+b)*6144 + n];
    int h = n/192, nl = n - h*192;
    if (nl < 128){
        q[((size_t)b*32+h)*192 + nl] = s;
    } else {
        int i2 = (nl-128)>>1;
        float other = __shfl_xor(s, 1);
        float c = cosb[b*32+i2], sn = sinb[b*32+i2];
        float* o = query + ((size_t)b*32+h)*576;
        if ((nl&1)==0) o[512+i2] = s*c - other*sn;
        else           o[544+i2] = s*c + other*sn;
    }
}

// ---------- reduce ckv partials + rmsnorm(512) + rope(last 64) -> latent[64][576]
__global__ __launch_bounds__(256) void reduce_kv_rope(const float* __restrict__ P,
        const float* __restrict__ w, const float* __restrict__ cosb, const float* __restrict__ sinb,
        float* __restrict__ latent, int S)
{
    const int b = blockIdx.x, t = threadIdx.x;
    __shared__ float vals[576];
    __shared__ float red[4];
    float ss = 0.f;
    for (int j=0;j<3;++j){
        int n = j*256+t;
        if (n < 576){
            float s=0.f;
            for (int sp=0;sp<S;++sp) s += P[((size_t)sp*64+b)*576 + n];
            vals[n]=s;
            if (n<512) ss += s*s;
        }
    }
#pragma unroll
    for (int off=32; off>=1; off>>=1) ss += __shfl_xor(ss, off, 64);
    if ((t&63)==0) red[t>>6]=ss;
    __syncthreads();
    float tot = red[0]+red[1]+red[2]+red[3];
    float rs = rsqrtf(tot/512.f + 1e-6f);
    for (int j=0;j<3;++j){
        int n = j*256+t;
        if (n<576){
            float o;
            if (n < 512) o = vals[n]*rs*w[n];
            else if (n < 544){ int i=n-512; o = vals[512+2*i]*cosb[b*32+i] - vals[513+2*i]*sinb[b*32+i]; }
            else            { int i=n-544; o = vals[513+2*i]*cosb[b*32+i] + vals[512+2*i]*sinb[b*32+i]; }
            latent[(size_t)b*576 + n] = o;
        }
    }
}

// ---------- ql_nope via MFMA
__global__ __launch_bounds__(256) void qlnope_mfma(const float* __restrict__ q,
        const float* __restrict__ wukt, float* __restrict__ query)
{
    __shared__ unsigned short Bh[4096], Bl[4096];
    const int h = blockIdx.x, r0 = blockIdx.y*128;
    const int tid = threadIdx.x;
    const int w = tid>>6, l = tid&63, lm = l&15, lg = l>>4;
    f32x4 acc[8];
#pragma unroll
    for (int i=0;i<8;++i){ acc[i][0]=0.f; acc[i][1]=0.f; acc[i][2]=0.f; acc[i][3]=0.f; }

    for (int ck=0; ck<4; ++ck){
        const int k0 = ck*32;
        unsigned short hh[2][8], ll[2][8]; int wid0 = tid*2;
#pragma unroll
        for (int wi=0; wi<2; ++wi){
            int wid = wid0 + wi;
            int ntile = wid>>6, kg = (wid>>4)&3, nl = wid&15;
            int n = r0 + ntile*16 + nl;
            const float* wp = wukt + (size_t)h*65536 + (size_t)(k0+kg*8)*512 + n;
#pragma unroll
            for (int j=0;j<8;++j){
                float v = wp[(size_t)j*512];
                hh[wi][j] = f2bf(v);
                ll[wi][j] = f2bf(v - bf2f(hh[wi][j]));
            }
        }
        __syncthreads();
#pragma unroll
        for (int wi=0; wi<2; ++wi){
            int wid = wid0 + wi;
            uint4 uh, ul;
            uh.x=(unsigned)hh[wi][0]|((unsigned)hh[wi][1]<<16); uh.y=(unsigned)hh[wi][2]|((unsigned)hh[wi][3]<<16);
            uh.z=(unsigned)hh[wi][4]|((unsigned)hh[wi][5]<<16); uh.w=(unsigned)hh[wi][6]|((unsigned)hh[wi][7]<<16);
            ul.x=(unsigned)ll[wi][0]|((unsigned)ll[wi][1]<<16); ul.y=(unsigned)ll[wi][2]|((unsigned)ll[wi][3]<<16);
            ul.z=(unsigned)ll[wi][4]|((unsigned)ll[wi][5]<<16); ul.w=(unsigned)ll[wi][6]|((unsigned)ll[wi][7]<<16);
            *(uint4*)(Bh + wid*8) = uh;
            *(uint4*)(Bl + wid*8) = ul;
        }
        __syncthreads();
        const int bb = w*16 + lm;
        const float* ap = q + ((size_t)bb*32 + h)*192 + k0 + lg*8;
        float4 a0 = *(const float4*)ap;
        float4 a1 = *(const float4*)(ap+4);
        union{uint4 u; bf16x8 v;} fh, fl;
        fh.u.x=pack2(a0.x,a0.y); fh.u.y=pack2(a0.z,a0.w);
        fh.u.z=pack2(a1.x,a1.y); fh.u.w=pack2(a1.z,a1.w);
        float r0f=a0.x-bf2f(f2bf(a0.x)), r1f=a0.y-bf2f(f2bf(a0.y));
        float r2f=a0.z-bf2f(f2bf(a0.z)), r3f=a0.w-bf2f(f2bf(a0.w));
        float r4f=a1.x-bf2f(f2bf(a1.x)), r5f=a1.y-bf2f(f2bf(a1.y));
        float r6f=a1.z-bf2f(f2bf(a1.z)), r7f=a1.w-bf2f(f2bf(a1.w));
        fl.u.x=pack2(r0f,r1f); fl.u.y=pack2(r2f,r3f);
        fl.u.z=pack2(r4f,r5f); fl.u.w=pack2(r6f,r7f);
#pragma unroll
        for (int nt=0;nt<8;++nt){
            const int fb = (nt*64 + lg*16 + lm)*8;
            bf16x8 fbh = *(const bf16x8*)(Bh + fb);
            bf16x8 fbl = *(const bf16x8*)(Bl + fb);
            acc[nt] = __builtin_amdgcn_mfma_f32_16x16x32_bf16(fh.v, fbh, acc[nt], 0,0,0);
            acc[nt] = __builtin_amdgcn_mfma_f32_16x16x32_bf16(fl.v, fbh, acc[nt], 0,0,0);
            acc[nt] = __builtin_amdgcn_mfma_f32_16x16x32_bf16(fh.v, fbl, acc[nt], 0,0,0);
        }
        __syncthreads();
    }
#pragma unroll
    for (int nt=0;nt<8;++nt){
        int r = r0 + nt*16 + lm;
#pragma unroll
        for (int qq=0;qq<4;++qq){
            int bb = w*16 + lg*4 + qq;
            query[((size_t)bb*32 + h)*576 + r] = acc[nt][qq];
        }
    }
}

// Vt flat layout: addr_u16(d,key) = (d>>2)*64 + ((d&3)^((d>>3)&3))*16 + key
static __device__ __forceinline__ int vt_addr(int d, int key){
    return (d>>2)*64 + (((d&3)^((d>>3)&3))<<4) + key;
}

// ---------- flash decode attention v5: global_load_lds dbuf fp32 K-tile, counted vmcnt
__global__ __launch_bounds__(256,1) void attn_mfma(const float* __restrict__ query,
        const float* __restrict__ kv, const float* __restrict__ latent,
        const int* __restrict__ slots, const int* __restrict__ seq_lens,
        float* __restrict__ Opart, float* __restrict__ Mpart, float* __restrict__ Lpart)
{
    __shared__ float Kf[2][16*576];               // 73728 B, granule-XOR source-swizzled
    __shared__ unsigned short Vt[8192];           // 16384 B
    __shared__ float S_s[2][32][16];              // 4096 B
    __shared__ unsigned short P_s[32][40];        // 2560 B (cols 16..31 zero)
    __shared__ float alpha_s[32];                 // 128 B   -> total 96896 B

    const int b = blockIdx.y, sp = blockIdx.x;
    const int tid = threadIdx.x;
    const int w = tid>>6, l = tid&63;
    const int lm = l&15, lg = l>>4;
    const int ht = w&1;
    const int dh = w>>1;
    const int seqlen = seq_lens[b];
    const int slot = slots[b];
    const int k0 = sp*KSPAN;
    const int myh = tid>>3, s5 = tid&7;

    {
        int id = tid*2;
        P_s[id>>4][16 + (id&15)] = 0;
        id++;
        P_s[id>>4][16 + (id&15)] = 0;
    }

    // Q fragments (this wave's d-half)
    bf16x8 qf[9];
    {
        const float* qrow = query + ((size_t)b*32 + ht*16 + lm)*576;
#pragma unroll
        for (int ss=0;ss<9;++ss){
            int d0 = (dh*9+ss)*32 + lg*8;
            float4 a = *(const float4*)(qrow + d0);
            float4 c = *(const float4*)(qrow + d0 + 4);
            union{uint4 u; bf16x8 v;} cv;
            cv.u.x=pack2(a.x,a.y); cv.u.y=pack2(a.z,a.w);
            cv.u.z=pack2(c.x,c.y); cv.u.w=pack2(c.z,c.w);
            qf[ss]=cv.v;
        }
    }

    // DMA stage: wave w covers rows 4w..4w+3 (9 KiB); source address carries inverse swizzle
    auto issue_tile = [&](int tt, int buf){
        const int gkb = k0 + tt*TK;
#pragma unroll
        for (int i=0;i<9;++i){
            int B = w*9216 + i*1024 + l*16;        // byte offset in 36864B tile
            int r = B / 2304;
            int gs = (B - r*2304) >> 4;
            int g  = gs ^ (r&7);
            int gk = gkb + r; if (gk > KCTX-1) gk = KCTX-1;
            const float* src = (gk==slot) ? (latent + (size_t)b*576 + g*4)
                                          : (kv + ((size_t)b*KCTX + gk)*576 + g*4);
            glds16(src, ((char*)&Kf[buf][0]) + w*9216 + i*1024);
        }
    };

    f32x4 oacc[16];
#pragma unroll
    for (int i=0;i<16;++i){ oacc[i][0]=0.f; oacc[i][1]=0.f; oacc[i][2]=0.f; oacc[i][3]=0.f; }
    float m_run = NEGINF, l_run = 0.f;

    issue_tile(0, 0);
    VM_BARRIER();

    for (int tt=0; tt<NTILE; ++tt){
        const int buf = tt&1;
        if (tt+1 < NTILE) issue_tile(tt+1, buf^1);   // in flight across the whole tile

        // ---- transpose Kf[buf] (d<512) -> Vt bf16
        {
            const int kg = tid&1;
            const int dq = tid>>1;           // granule 0..127, d0 = dq*4
            float4 rv[8];
#pragma unroll
            for (int i=0;i<8;++i){
                int r = kg*8 + i;
                rv[i] = *(const float4*)(&Kf[buf][r*576 + ((dq ^ (r&7))<<2)]);
            }
#pragma unroll
            for (int j=0;j<4;++j){
                const float* f0 = (const float*)&rv[0];
                const float* f1 = (const float*)&rv[1];
                const float* f2 = (const float*)&rv[2];
                const float* f3 = (const float*)&rv[3];
                const float* f4 = (const float*)&rv[4];
                const float* f5 = (const float*)&rv[5];
                const float* f6 = (const float*)&rv[6];
                const float* f7 = (const float*)&rv[7];
                uint4 o;
                o.x = pack2(f0[j], f1[j]); o.y = pack2(f2[j], f3[j]);
                o.z = pack2(f4[j], f5[j]); o.w = pack2(f6[j], f7[j]);
                *(uint4*)(Vt + vt_addr(dq*4+j, kg*8)) = o;
            }
        }
        // ---- QK^T partial (convert K rows from fp32 LDS on the fly)
        {
            f32x4 sacc; sacc[0]=0.f; sacc[1]=0.f; sacc[2]=0.f; sacc[3]=0.f;
            const float* kb = &Kf[buf][lm*576];
            const int sw = lm&7;
            __builtin_amdgcn_s_setprio(1);
#pragma unroll
            for (int ss=0;ss<9;++ss){
                int g = dh*72 + ss*8 + lg*2;
                float4 fa = *(const float4*)(kb + ((g ^ sw)<<2));
                float4 fb = *(const float4*)(kb + (((g+1) ^ sw)<<2));
                union{uint4 u; bf16x8 v;} cv;
                cv.u.x = pack2(fa.x, fa.y); cv.u.y = pack2(fa.z, fa.w);
                cv.u.z = pack2(fb.x, fb.y); cv.u.w = pack2(fb.z, fb.w);
                sacc = __builtin_amdgcn_mfma_f32_16x16x32_bf16(qf[ss], cv.v, sacc, 0,0,0);
            }
            __builtin_amdgcn_s_setprio(0);
#pragma unroll
            for (int r=0;r<4;++r) S_s[dh][ht*16 + (lg<<2) + r][lm] = sacc[r];
        }
        LGKM_BARRIER();                    // #1 (vmcnt NOT drained)

        // ---- online softmax
        {
            const int kbase = k0 + tt*TK;
            float sc[2];
#pragma unroll
            for (int j=0;j<2;++j){
                int k = s5 + 8*j;
                float v = (S_s[0][myh][k] + S_s[1][myh][k])*SM_SCALE;
                sc[j] = (kbase + k < seqlen) ? v : NEGINF;
            }
            float tmax = fmaxf(sc[0],sc[1]);
            tmax = fmaxf(tmax, __shfl_xor(tmax,1));
            tmax = fmaxf(tmax, __shfl_xor(tmax,2));
            tmax = fmaxf(tmax, __shfl_xor(tmax,4));
            float mnew = fmaxf(m_run, tmax);
            float al = __expf(m_run - mnew);
            float ps = 0.f;
#pragma unroll
            for (int j=0;j<2;++j){
                float pv = (sc[j] > 0.5f*NEGINF) ? __expf(sc[j]-mnew) : 0.f;
                ps += pv;
                P_s[myh][s5 + 8*j] = f2bf(pv);
            }
            ps += __shfl_xor(ps,1); ps += __shfl_xor(ps,2); ps += __shfl_xor(ps,4);
            l_run = l_run*al + ps;
            m_run = mnew;
            if (s5==0) alpha_s[myh] = al;
        }
        LGKM_BARRIER();                    // #2

        // ---- PV
        {
            float al4[4];
#pragma unroll
            for (int r=0;r<4;++r) al4[r] = alpha_s[ht*16 + (lg<<2) + r];
            bf16x8 pa = *(const bf16x8*)(&P_s[ht*16+lm][lg*8]);
            __builtin_amdgcn_s_setprio(1);
#pragma unroll
            for (int nt=0;nt<16;++nt){
                f32x4 o = oacc[nt];
                o[0]*=al4[0]; o[1]*=al4[1]; o[2]*=al4[2]; o[3]*=al4[3];
                int r = dh*256 + nt*16 + lm;
                bf16x8 bv = *(const bf16x8*)(Vt + vt_addr(r, (lg&1)*8));
                oacc[nt] = __builtin_amdgcn_mfma_f32_16x16x32_bf16(pa, bv, o, 0,0,0);
            }
            __builtin_amdgcn_s_setprio(0);
        }
        VM_BARRIER();                      // wait next tile's DMA (had full tile to land)
    }

    const int obase = (b*NSPLIT+sp)*32;
#pragma unroll
    for (int nt=0;nt<16;++nt){
        int r = dh*256 + nt*16 + lm;
#pragma unroll
        for (int qq=0;qq<4;++qq){
            int h = ht*16 + (lg<<2) + qq;
            Opart[((size_t)(obase+h))*512 + r] = oacc[nt][qq];
        }
    }
    if (s5==0){ Mpart[obase+myh]=m_run; Lpart[obase+myh]=l_run; }
}

// ---------- merge NSPLIT flash partials -> attn[b][h][512]
__global__ __launch_bounds__(256) void merge_attn(const float* __restrict__ Opart,
        const float* __restrict__ Mpart, const float* __restrict__ Lpart, float* __restrict__ attn)
{
    const int bh = blockIdx.x;
    const int b = bh>>5, h = bh&31;
    const int t = threadIdx.x;
    float m[NSPLIT], lw[NSPLIT];
    float M = NEGINF;
#pragma unroll
    for (int s=0;s<NSPLIT;++s){ m[s] = Mpart[(b*NSPLIT+s)*32 + h]; M = fmaxf(M,m[s]); }
    float L = 0.f;
#pragma unroll
    for (int s=0;s<NSPLIT;++s){ lw[s] = __expf(m[s]-M); L += lw[s]*Lpart[(b*NSPLIT+s)*32+h]; }
    float inv = 1.f/L;
#pragma unroll
    for (int j=0;j<2;++j){
        int r = j*256+t;
        float o = 0.f;
#pragma unroll
        for (int s=0;s<NSPLIT;++s)
            o += lw[s]*Opart[((size_t)((b*NSPLIT+s)*32) + h)*512 + r];
        attn[((size_t)b*32+h)*512 + r] = o*inv;
    }
}

// ---------- av_uv via MFMA + fused hi/lo pack of ao (A for w_o GEMM)
__global__ __launch_bounds__(256) void av_uv_mfma(const float* __restrict__ attn,
        const float* __restrict__ wuv,
        unsigned short* __restrict__ Hi, unsigned short* __restrict__ Lo)
{
    __shared__ unsigned short Bh[4096], Bl[4096];
    const int h = blockIdx.x;
    const int tid = threadIdx.x;
    const int w = tid>>6, l = tid&63, lm = l&15, lg = l>>4;
    f32x4 acc[8];
#pragma unroll
    for (int i=0;i<8;++i){ acc[i][0]=0.f; acc[i][1]=0.f; acc[i][2]=0.f; acc[i][3]=0.f; }

    for (int ck=0; ck<16; ++ck){
        const int k0 = ck*32;
        unsigned short hh[2][8], ll[2][8]; int wid0 = tid*2;
#pragma unroll
        for (int wi=0; wi<2; ++wi){
            int wid = wid0 + wi;
            int ntile = wid>>6, kg = (wid>>4)&3, nl = wid&15;
            int n = ntile*16 + nl;
            const float* wp = wuv + (size_t)h*65536 + (size_t)(k0+kg*8)*128 + n;
#pragma unroll
            for (int j=0;j<8;++j){
                float v = wp[(size_t)j*128];
                hh[wi][j] = f2bf(v);
                ll[wi][j] = f2bf(v - bf2f(hh[wi][j]));
            }
        }
        __syncthreads();
#pragma unroll
        for (int wi=0; wi<2; ++wi){
            int wid = wid0 + wi;
            uint4 uh, ul;
            uh.x=(unsigned)hh[wi][0]|((unsigned)hh[wi][1]<<16); uh.y=(unsigned)hh[wi][2]|((unsigned)hh[wi][3]<<16);
            uh.z=(unsigned)hh[wi][4]|((unsigned)hh[wi][5]<<16); uh.w=(unsigned)hh[wi][6]|((unsigned)hh[wi][7]<<16);
            ul.x=(unsigned)ll[wi][0]|((unsigned)ll[wi][1]<<16); ul.y=(unsigned)ll[wi][2]|((unsigned)ll[wi][3]<<16);
            ul.z=(unsigned)ll[wi][4]|((unsigned)ll[wi][5]<<16); ul.w=(unsigned)ll[wi][6]|((unsigned)ll[wi][7]<<16);
            *(uint4*)(Bh + wid*8) = uh;
            *(uint4*)(Bl + wid*8) = ul;
        }
        __syncthreads();
        const int bb = w*16 + lm;
        const float* ap = attn + ((size_t)bb*32 + h)*512 + k0 + lg*8;
        float4 a0 = *(const float4*)ap;
        float4 a1 = *(const float4*)(ap+4);
        union{uint4 u; bf16x8 v;} fh, fl;
        fh.u.x=pack2(a0.x,a0.y); fh.u.y=pack2(a0.z,a0.w);
        fh.u.z=pack2(a1.x,a1.y); fh.u.w=pack2(a1.z,a1.w);
        float r0f=a0.x-bf2f(f2bf(a0.x)), r1f=a0.y-bf2f(f2bf(a0.y));
        float r2f=a0.z-bf2f(f2bf(a0.z)), r3f=a0.w-bf2f(f2bf(a0.w));
        float r4f=a1.x-bf2f(f2bf(a1.x)), r5f=a1.y-bf2f(f2bf(a1.y));
        float r6f=a1.z-bf2f(f2bf(a1.z)), r7f=a1.w-bf2f(f2bf(a1.w));
        fl.u.x=pack2(r0f,r1f); fl.u.y=pack2(r2f,r3f);
        fl.u.z=pack2(r4f,r5f); fl.u.w=pack2(r6f,r7f);
#pragma unroll
        for (int nt=0;nt<8;++nt){
            const int fb = (nt*64 + lg*16 + lm)*8;
            bf16x8 fbh = *(const bf16x8*)(Bh + fb);
            bf16x8 fbl = *(const bf16x8*)(Bl + fb);
            acc[nt] = __builtin_amdgcn_mfma_f32_16x16x32_bf16(fh.v, fbh, acc[nt], 0,0,0);
            acc[nt] = __builtin_amdgcn_mfma_f32_16x16x32_bf16(fl.v, fbh, acc[nt], 0,0,0);
            acc[nt] = __builtin_amdgcn_mfma_f32_16x16x32_bf16(fh.v, fbl, acc[nt], 0,0,0);
        }
        __syncthreads();
    }
#pragma unroll
    for (int nt=0;nt<8;++nt){
#pragma unroll
        for (int qq=0;qq<4;++qq){
            float val = acc[nt][qq];
            int bb = w*16 + lg*4 + qq;
            int k = h*128 + nt*16 + lm;
            unsigned short hv = f2bf(val);
            unsigned short lv = f2bf(val - bf2f(hv));
            size_t ui = (size_t)(k>>3)*512 + bb*8 + (k&7);
            Hi[ui] = hv; Lo[ui] = lv;
        }
    }
}

extern "C" void kernel_launch(void* const* d_in, const int* in_sizes, int n_in,
                              void* d_out, int out_size, void* d_ws, size_t ws_size,
                              hipStream_t stream)
{
    const float* hidden = (const float*)d_in[0];
    const float* cosb   = (const float*)d_in[1];
    const float* sinb   = (const float*)d_in[2];
    const float* kv     = (const float*)d_in[3];
    const float* w_q_a  = (const float*)d_in[4];
    const float* q_ln   = (const float*)d_in[5];
    const float* w_q_b  = (const float*)d_in[6];
    const float* w_kv_a = (const float*)d_in[7];
    const float* kv_ln  = (const float*)d_in[8];
    const float* w_uk_t = (const float*)d_in[9];
    const float* w_uv   = (const float*)d_in[10];
    const float* w_o    = (const float*)d_in[11];
    const int* slots    = (const int*)d_in[12];
    const int* seqlens  = (const int*)d_in[13];
    float* out = (float*)d_out;

    float* W = (float*)d_ws;
    float* P      = W;                   // gemm partials / attn Opart
    float* q      = W + 12582912;
    float* latent = W + 12976128;
    float* query  = W + 13012992;
    float* Mp     = W + 14192640;
    float* Lp     = W + 14217216;
    float* attn   = W + 14241792;
    unsigned short* pkhid_h = (unsigned short*)(W + 15290368);
    unsigned short* pkhid_l = (unsigned short*)(W + 15519744);
    unsigned short* pkqc_h  = (unsigned short*)(W + 15749120);
    unsigned short* pkqc_l  = (unsigned short*)(W + 15798272);
    unsigned short* pkao_h  = (unsigned short*)(W + 15847424);
    unsigned short* pkao_l  = (unsigned short*)(W + 15978496);

    // q branch
    hipLaunchKernelGGL(pack_a, dim3(224), dim3(256), 0, stream, hidden, pkhid_h, pkhid_l, 7168);
    hipLaunchKernelGGL(gemm_mfma, dim3(24,28), dim3(256), 0, stream, pkhid_h, pkhid_l, w_q_a, P, 1536, 8);
    hipLaunchKernelGGL(rms_qc_pack, dim3(64), dim3(256), 0, stream, P, q_ln, pkqc_h, pkqc_l, 28);
    hipLaunchKernelGGL(gemm_mfma, dim3(96,6), dim3(256), 0, stream, pkqc_h, pkqc_l, w_q_b, P, 6144, 8);
    hipLaunchKernelGGL(finish_q, dim3(1536), dim3(256), 0, stream, P, cosb, sinb, q, query, 6);
    // kv branch
    hipLaunchKernelGGL(gemm_mfma, dim3(9,56), dim3(256), 0, stream, pkhid_h, pkhid_l, w_kv_a, P, 576, 4);
    hipLaunchKernelGGL(reduce_kv_rope, dim3(64), dim3(256), 0, stream, P, kv_ln, cosb, sinb, latent, 56);
    // query nope
    hipLaunchKernelGGL(qlnope_mfma, dim3(32,4), dim3(256), 0, stream, q, w_uk_t, query);
    // attention
    hipLaunchKernelGGL(attn_mfma, dim3(NSPLIT,64), dim3(256), 0, stream,
                       query, kv, latent, slots, seqlens, P, Mp, Lp);
    hipLaunchKernelGGL(merge_attn, dim3(2048), dim3(256), 0, stream, P, Mp, Lp, attn);
    hipLaunchKernelGGL(av_uv_mfma, dim3(32), dim3(256), 0, stream, attn, w_uv, pkao_h, pkao_l);
    // output projection
    hipLaunchKernelGGL(gemm_mfma, dim3(112,8), dim3(256), 0, stream, pkao_h, pkao_l, w_o, P, 7168, 16);
    hipLaunchKernelGGL(reduce_sum, dim3(1792), dim3(256), 0, stream, P, out, 8, 7168);
}

// Round 9
// 387.733 us; speedup vs baseline: 2.1231x; 1.1094x over previous
//
#include <hip/hip_runtime.h>
#include <stdint.h>

#define NB 64
#define NH 32
#define KCTX 4096
#define HID 7168
#define QLORA 1536
#define KVL 512
#define DTOT 576
#define NSPLIT 4
#define KSPAN 1024
#define NTILE 64           // KSPAN/16
#define TK 16
#define SM_SCALE 0.07216878364870323f  // 1/sqrt(192)
#define NEGINF (-3.0e38f)

typedef __attribute__((ext_vector_type(4))) float f32x4;
typedef __attribute__((ext_vector_type(8))) __bf16 bf16x8;

#define LGKM_BARRIER() do{ asm volatile("s_waitcnt lgkmcnt(0)" ::: "memory"); __builtin_amdgcn_s_barrier(); } while(0)

static __device__ __forceinline__ void glds16(const void* g, void* s){
    __builtin_amdgcn_global_load_lds((const __attribute__((address_space(1))) void*)g,
                                     (__attribute__((address_space(3))) void*)s, 16, 0, 0);
}

static __device__ __forceinline__ unsigned short f2bf(float f){
    union{__bf16 h; unsigned short s;} x; x.h = (__bf16)f; return x.s;
}
static __device__ __forceinline__ float bf2f(unsigned short h){
    union{unsigned i;float f;}x; x.i=((unsigned)h)<<16; return x.f;
}
static __device__ __forceinline__ unsigned pack2(float a, float b){
    union{__bf16 h[2]; unsigned u;} x; x.h[0]=(__bf16)a; x.h[1]=(__bf16)b; return x.u;
}

// ---------- pack A[64][K] fp32 -> frag-ready bf16 hi/lo words: word idx = (k>>3)*64+m
__global__ __launch_bounds__(256) void pack_a(const float* __restrict__ A,
        unsigned short* __restrict__ Hi, unsigned short* __restrict__ Lo, int K)
{
    int idx = blockIdx.x*256 + threadIdx.x;
    int m = idx & 63, kb = idx >> 6;
    const float* src = A + (size_t)m*K + kb*8;
    float v[8];
    *(float4*)(v)   = *(const float4*)(src);
    *(float4*)(v+4) = *(const float4*)(src+4);
    unsigned short h[8], l[8];
#pragma unroll
    for (int j=0;j<8;++j){
        h[j] = f2bf(v[j]);
        l[j] = f2bf(v[j] - bf2f(h[j]));
    }
    uint4 uh, ul;
    uh.x=(unsigned)h[0]|((unsigned)h[1]<<16); uh.y=(unsigned)h[2]|((unsigned)h[3]<<16);
    uh.z=(unsigned)h[4]|((unsigned)h[5]<<16); uh.w=(unsigned)h[6]|((unsigned)h[7]<<16);
    ul.x=(unsigned)l[0]|((unsigned)l[1]<<16); ul.y=(unsigned)l[2]|((unsigned)l[3]<<16);
    ul.z=(unsigned)l[4]|((unsigned)l[5]<<16); ul.w=(unsigned)l[6]|((unsigned)l[7]<<16);
    *(uint4*)(Hi + (size_t)idx*8) = uh;
    *(uint4*)(Lo + (size_t)idx*8) = ul;
}

// ---------- shared MFMA skinny-GEMM core (double-buffered LDS, 1 barrier/step)
static __device__ __forceinline__ void gemm_core(
        const unsigned short* __restrict__ Ahi, const unsigned short* __restrict__ Alo,
        const float* __restrict__ Wm, float* __restrict__ P, int N, int ksteps,
        int bx, int by,
        unsigned short* Ah, unsigned short* Al, unsigned short* Bh, unsigned short* Bl)
{
    const int tid = threadIdx.x;
    const int w = tid>>6, l = tid&63, lm = l&15, lg = l>>4;
    const int n0 = bx*64;
    const int s  = by;
    const int mn = tid&63, ks = tid>>6;
    const int widx = ((mn>>4)*64 + ks*16 + (mn&15));

    f32x4 acc[4];
#pragma unroll
    for (int i=0;i<4;++i){ acc[i][0]=0.f; acc[i][1]=0.f; acc[i][2]=0.f; acc[i][3]=0.f; }

    uint4 ah4, al4; float wv[8];
    auto load_raw = [&](int t){
        const int k0 = (s*ksteps + t)*32;
        size_t gidx = (size_t)((k0>>3) + ks)*64 + mn;
        ah4 = *(const uint4*)(Ahi + gidx*8);
        al4 = *(const uint4*)(Alo + gidx*8);
        const float* wp = Wm + (size_t)(k0 + ks*8)*N + n0 + mn;
#pragma unroll
        for (int j=0;j<8;++j) wv[j] = wp[(size_t)j*N];
    };
    auto cvt_write = [&](int buf){
        unsigned short h[8], lo[8];
#pragma unroll
        for (int j=0;j<8;++j){
            h[j]  = f2bf(wv[j]);
            lo[j] = f2bf(wv[j] - bf2f(h[j]));
        }
        uint4 bh4, bl4;
        bh4.x=(unsigned)h[0]|((unsigned)h[1]<<16); bh4.y=(unsigned)h[2]|((unsigned)h[3]<<16);
        bh4.z=(unsigned)h[4]|((unsigned)h[5]<<16); bh4.w=(unsigned)h[6]|((unsigned)h[7]<<16);
        bl4.x=(unsigned)lo[0]|((unsigned)lo[1]<<16); bl4.y=(unsigned)lo[2]|((unsigned)lo[3]<<16);
        bl4.z=(unsigned)lo[4]|((unsigned)lo[5]<<16); bl4.w=(unsigned)lo[6]|((unsigned)lo[7]<<16);
        *(uint4*)(Ah + buf*2048 + widx*8) = ah4;
        *(uint4*)(Al + buf*2048 + widx*8) = al4;
        *(uint4*)(Bh + buf*2048 + widx*8) = bh4;
        *(uint4*)(Bl + buf*2048 + widx*8) = bl4;
    };

    load_raw(0);
    for (int t=0; t<ksteps; ++t){
        const int buf = t&1;
        cvt_write(buf);
        __syncthreads();
        if (t+1 < ksteps) load_raw(t+1);
        const int fa = buf*2048 + (w*64 + lg*16 + lm)*8;
        bf16x8 fah = *(const bf16x8*)(Ah + fa);
        bf16x8 fal = *(const bf16x8*)(Al + fa);
#pragma unroll
        for (int nt=0;nt<4;++nt){
            const int fb = buf*2048 + (nt*64 + lg*16 + lm)*8;
            bf16x8 fbh = *(const bf16x8*)(Bh + fb);
            bf16x8 fbl = *(const bf16x8*)(Bl + fb);
            acc[nt] = __builtin_amdgcn_mfma_f32_16x16x32_bf16(fah, fbh, acc[nt], 0,0,0);
            acc[nt] = __builtin_amdgcn_mfma_f32_16x16x32_bf16(fal, fbh, acc[nt], 0,0,0);
            acc[nt] = __builtin_amdgcn_mfma_f32_16x16x32_bf16(fah, fbl, acc[nt], 0,0,0);
        }
        __syncthreads();
    }
#pragma unroll
    for (int nt=0;nt<4;++nt){
        int n = n0 + nt*16 + lm;
#pragma unroll
        for (int r=0;r<4;++r){
            int m = w*16 + lg*4 + r;
            P[((size_t)s*64 + m)*N + n] = acc[nt][r];
        }
    }
}

__global__ __launch_bounds__(256) void gemm_mfma(
        const unsigned short* __restrict__ Ahi, const unsigned short* __restrict__ Alo,
        const float* __restrict__ Wm, float* __restrict__ P, int N, int ksteps)
{
    __shared__ unsigned short Ah[2*2048], Al[2*2048], Bh[2*2048], Bl[2*2048];
    gemm_core(Ahi, Alo, Wm, P, N, ksteps, blockIdx.x, blockIdx.y, Ah, Al, Bh, Bl);
}

// two independent GEMMs in one launch (w_q_a || w_kv_a)
__global__ __launch_bounds__(256) void gemm_dual(
        const unsigned short* __restrict__ Ahi, const unsigned short* __restrict__ Alo,
        const float* __restrict__ W0, float* __restrict__ P0, int N0, int ks0, int nbx0, int nblk0,
        const float* __restrict__ W1, float* __restrict__ P1, int N1, int ks1, int nbx1)
{
    __shared__ unsigned short Ah[2*2048], Al[2*2048], Bh[2*2048], Bl[2*2048];
    int bid = blockIdx.x;
    if (bid < nblk0){
        gemm_core(Ahi, Alo, W0, P0, N0, ks0, bid%nbx0, bid/nbx0, Ah, Al, Bh, Bl);
    } else {
        bid -= nblk0;
        gemm_core(Ahi, Alo, W1, P1, N1, ks1, bid%nbx1, bid/nbx1, Ah, Al, Bh, Bl);
    }
}

// ---------- rms_qc_pack core
static __device__ __forceinline__ void rms_core(const float* __restrict__ P,
        const float* __restrict__ w, unsigned short* __restrict__ Hi,
        unsigned short* __restrict__ Lo, int S, int b, float* red)
{
    const int t = threadIdx.x;
    float v[6]; float ss = 0.f;
#pragma unroll
    for (int j=0;j<6;++j){
        int n = j*256 + t;
        float s = 0.f;
        for (int sp=0; sp<S; ++sp) s += P[((size_t)sp*64+b)*1536 + n];
        v[j] = s; ss += s*s;
    }
#pragma unroll
    for (int off=32; off>=1; off>>=1) ss += __shfl_xor(ss, off, 64);
    if ((t&63)==0) red[t>>6] = ss;
    __syncthreads();
    float tot = red[0]+red[1]+red[2]+red[3];
    float rs = rsqrtf(tot/1536.f + 1e-6f);
#pragma unroll
    for (int j=0;j<6;++j){
        int n = j*256+t;
        float val = v[j]*rs*w[n];
        unsigned short hs = f2bf(val);
        unsigned short ls = f2bf(val - bf2f(hs));
        size_t ui = (size_t)(n>>3)*512 + b*8 + (n&7);
        Hi[ui] = hs; Lo[ui] = ls;
    }
}

// ---------- reduce_kv_rope core
static __device__ __forceinline__ void kvrope_core(const float* __restrict__ P,
        const float* __restrict__ w, const float* __restrict__ cosb, const float* __restrict__ sinb,
        float* __restrict__ latent, int S, int b, float* vals, float* red)
{
    const int t = threadIdx.x;
    float ss = 0.f;
    for (int j=0;j<3;++j){
        int n = j*256+t;
        if (n < 576){
            float s=0.f;
            for (int sp=0;sp<S;++sp) s += P[((size_t)sp*64+b)*576 + n];
            vals[n]=s;
            if (n<512) ss += s*s;
        }
    }
#pragma unroll
    for (int off=32; off>=1; off>>=1) ss += __shfl_xor(ss, off, 64);
    if ((t&63)==0) red[t>>6]=ss;
    __syncthreads();
    float tot = red[0]+red[1]+red[2]+red[3];
    float rs = rsqrtf(tot/512.f + 1e-6f);
    for (int j=0;j<3;++j){
        int n = j*256+t;
        if (n<576){
            float o;
            if (n < 512) o = vals[n]*rs*w[n];
            else if (n < 544){ int i=n-512; o = vals[512+2*i]*cosb[b*32+i] - vals[513+2*i]*sinb[b*32+i]; }
            else            { int i=n-544; o = vals[513+2*i]*cosb[b*32+i] + vals[512+2*i]*sinb[b*32+i]; }
            latent[(size_t)b*576 + n] = o;
        }
    }
}

// rms_qc_pack || reduce_kv_rope in one launch
__global__ __launch_bounds__(256) void norm_dual(
        const float* __restrict__ Pq, const float* __restrict__ qw,
        unsigned short* __restrict__ Hi, unsigned short* __restrict__ Lo, int Sq,
        const float* __restrict__ Pkv, const float* __restrict__ kvw,
        const float* __restrict__ cosb, const float* __restrict__ sinb,
        float* __restrict__ latent, int Skv)
{
    __shared__ float vals[576];
    __shared__ float red[4];
    if (blockIdx.x < 64) rms_core(Pq, qw, Hi, Lo, Sq, blockIdx.x, red);
    else                 kvrope_core(Pkv, kvw, cosb, sinb, latent, Skv, blockIdx.x-64, vals, red);
}

// ---------- generic partial reduce
__global__ __launch_bounds__(256) void reduce_sum(const float* __restrict__ P,
        float* __restrict__ out, int S, int N)
{
    int i = blockIdx.x*256 + threadIdx.x;
    int b = i / N, n = i - b*N;
    float s = 0.f;
    for (int sp=0; sp<S; ++sp) s += P[((size_t)sp*64+b)*N + n];
    out[i] = s;
}

// ---------- finish q: reduce partials; n<128 -> q fp32; rope -> query[512..]
__global__ __launch_bounds__(256) void finish_q(const float* __restrict__ P,
        const float* __restrict__ cosb, const float* __restrict__ sinb,
        float* __restrict__ q, float* __restrict__ query, int S)
{
    int i = blockIdx.x*256 + threadIdx.x;
    int b = i / 6144, n = i - b*6144;
    float s = 0.f;
    for (int sp=0; sp<S; ++sp) s += P[((size_t)sp*64+b)*6144 + n];
    int h = n/192, nl = n - h*192;
    if (nl < 128){
        q[((size_t)b*32+h)*192 + nl] = s;
    } else {
        int i2 = (nl-128)>>1;
        float other = __shfl_xor(s, 1);
        float c = cosb[b*32+i2], sn = sinb[b*32+i2];
        float* o = query + ((size_t)b*32+h)*576;
        if ((nl&1)==0) o[512+i2] = s*c - other*sn;
        else           o[544+i2] = s*c + other*sn;
    }
}

// ---------- ql_nope via MFMA
__global__ __launch_bounds__(256) void qlnope_mfma(const float* __restrict__ q,
        const float* __restrict__ wukt, float* __restrict__ query)
{
    __shared__ unsigned short Bh[4096], Bl[4096];
    const int h = blockIdx.x, r0 = blockIdx.y*128;
    const int tid = threadIdx.x;
    const int w = tid>>6, l = tid&63, lm = l&15, lg = l>>4;
    f32x4 acc[8];
#pragma unroll
    for (int i=0;i<8;++i){ acc[i][0]=0.f; acc[i][1]=0.f; acc[i][2]=0.f; acc[i][3]=0.f; }

    for (int ck=0; ck<4; ++ck){
        const int k0 = ck*32;
        unsigned short hh[2][8], ll[2][8]; int wid0 = tid*2;
#pragma unroll
        for (int wi=0; wi<2; ++wi){
            int wid = wid0 + wi;
            int ntile = wid>>6, kg = (wid>>4)&3, nl = wid&15;
            int n = r0 + ntile*16 + nl;
            const float* wp = wukt + (size_t)h*65536 + (size_t)(k0+kg*8)*512 + n;
#pragma unroll
            for (int j=0;j<8;++j){
                float v = wp[(size_t)j*512];
                hh[wi][j] = f2bf(v);
                ll[wi][j] = f2bf(v - bf2f(hh[wi][j]));
            }
        }
        __syncthreads();
#pragma unroll
        for (int wi=0; wi<2; ++wi){
            int wid = wid0 + wi;
            uint4 uh, ul;
            uh.x=(unsigned)hh[wi][0]|((unsigned)hh[wi][1]<<16); uh.y=(unsigned)hh[wi][2]|((unsigned)hh[wi][3]<<16);
            uh.z=(unsigned)hh[wi][4]|((unsigned)hh[wi][5]<<16); uh.w=(unsigned)hh[wi][6]|((unsigned)hh[wi][7]<<16);
            ul.x=(unsigned)ll[wi][0]|((unsigned)ll[wi][1]<<16); ul.y=(unsigned)ll[wi][2]|((unsigned)ll[wi][3]<<16);
            ul.z=(unsigned)ll[wi][4]|((unsigned)ll[wi][5]<<16); ul.w=(unsigned)ll[wi][6]|((unsigned)ll[wi][7]<<16);
            *(uint4*)(Bh + wid*8) = uh;
            *(uint4*)(Bl + wid*8) = ul;
        }
        __syncthreads();
        const int bb = w*16 + lm;
        const float* ap = q + ((size_t)bb*32 + h)*192 + k0 + lg*8;
        float4 a0 = *(const float4*)ap;
        float4 a1 = *(const float4*)(ap+4);
        union{uint4 u; bf16x8 v;} fh, fl;
        fh.u.x=pack2(a0.x,a0.y); fh.u.y=pack2(a0.z,a0.w);
        fh.u.z=pack2(a1.x,a1.y); fh.u.w=pack2(a1.z,a1.w);
        float r0f=a0.x-bf2f(f2bf(a0.x)), r1f=a0.y-bf2f(f2bf(a0.y));
        float r2f=a0.z-bf2f(f2bf(a0.z)), r3f=a0.w-bf2f(f2bf(a0.w));
        float r4f=a1.x-bf2f(f2bf(a1.x)), r5f=a1.y-bf2f(f2bf(a1.y));
        float r6f=a1.z-bf2f(f2bf(a1.z)), r7f=a1.w-bf2f(f2bf(a1.w));
        fl.u.x=pack2(r0f,r1f); fl.u.y=pack2(r2f,r3f);
        fl.u.z=pack2(r4f,r5f); fl.u.w=pack2(r6f,r7f);
#pragma unroll
        for (int nt=0;nt<8;++nt){
            const int fb = (nt*64 + lg*16 + lm)*8;
            bf16x8 fbh = *(const bf16x8*)(Bh + fb);
            bf16x8 fbl = *(const bf16x8*)(Bl + fb);
            acc[nt] = __builtin_amdgcn_mfma_f32_16x16x32_bf16(fh.v, fbh, acc[nt], 0,0,0);
            acc[nt] = __builtin_amdgcn_mfma_f32_16x16x32_bf16(fl.v, fbh, acc[nt], 0,0,0);
            acc[nt] = __builtin_amdgcn_mfma_f32_16x16x32_bf16(fh.v, fbl, acc[nt], 0,0,0);
        }
        __syncthreads();
    }
#pragma unroll
    for (int nt=0;nt<8;++nt){
        int r = r0 + nt*16 + lm;
#pragma unroll
        for (int qq=0;qq<4;++qq){
            int bb = w*16 + lg*4 + qq;
            query[((size_t)bb*32 + h)*576 + r] = acc[nt][qq];
        }
    }
}

// Vt flat layout: addr_u16(d,key) = (d>>2)*64 + ((d&3)^((d>>3)&3))*16 + key
static __device__ __forceinline__ int vt_addr(int d, int key){
    return (d>>2)*64 + (((d&3)^((d>>3)&3))<<4) + key;
}

// ---------- flash decode attention v6: triple-buffered global_load_lds, counted vmcnt(9)
__global__ __launch_bounds__(256,1) void attn_mfma(const float* __restrict__ query,
        const float* __restrict__ kv, const float* __restrict__ latent,
        const int* __restrict__ slots, const int* __restrict__ seq_lens,
        float* __restrict__ Opart, float* __restrict__ Mpart, float* __restrict__ Lpart)
{
    __shared__ float Kf[3][16*576];               // 110592 B, granule-XOR source-swizzled
    __shared__ unsigned short Vt[8192];           // 16384 B
    __shared__ float S_s[2][32][16];              // 4096 B
    __shared__ unsigned short P_s[32][40];        // 2560 B (cols 16..31 zero)
    __shared__ float alpha_s[32];                 // 128 B   -> total 133760 B

    const int b = blockIdx.y, sp = blockIdx.x;
    const int tid = threadIdx.x;
    const int w = tid>>6, l = tid&63;
    const int lm = l&15, lg = l>>4;
    const int ht = w&1;
    const int dh = w>>1;
    const int seqlen = seq_lens[b];
    const int slot = slots[b];
    const int k0 = sp*KSPAN;
    const int myh = tid>>3, s5 = tid&7;

    {
        int id = tid*2;
        P_s[id>>4][16 + (id&15)] = 0;
        id++;
        P_s[id>>4][16 + (id&15)] = 0;
    }

    bf16x8 qf[9];
    {
        const float* qrow = query + ((size_t)b*32 + ht*16 + lm)*576;
#pragma unroll
        for (int ss=0;ss<9;++ss){
            int d0 = (dh*9+ss)*32 + lg*8;
            float4 a = *(const float4*)(qrow + d0);
            float4 c = *(const float4*)(qrow + d0 + 4);
            union{uint4 u; bf16x8 v;} cv;
            cv.u.x=pack2(a.x,a.y); cv.u.y=pack2(a.z,a.w);
            cv.u.z=pack2(c.x,c.y); cv.u.w=pack2(c.z,c.w);
            qf[ss]=cv.v;
        }
    }

    // DMA stage: 9 glds16 per wave per tile; source address carries inverse swizzle
    auto issue_tile = [&](int tt, int buf){
        const int gkb = k0 + tt*TK;
#pragma unroll
        for (int i=0;i<9;++i){
            int B = w*9216 + i*1024 + l*16;        // byte offset in 36864B tile
            int r = B / 2304;
            int gs = (B - r*2304) >> 4;
            int g  = gs ^ (r&7);
            int gk = gkb + r; if (gk > KCTX-1) gk = KCTX-1;
            const float* src = (gk==slot) ? (latent + (size_t)b*576 + g*4)
                                          : (kv + ((size_t)b*KCTX + gk)*576 + g*4);
            glds16(src, ((char*)&Kf[buf][0]) + w*9216 + i*1024);
        }
    };

    f32x4 oacc[16];
#pragma unroll
    for (int i=0;i<16;++i){ oacc[i][0]=0.f; oacc[i][1]=0.f; oacc[i][2]=0.f; oacc[i][3]=0.f; }
    float m_run = NEGINF, l_run = 0.f;

    issue_tile(0, 0);
    issue_tile(1, 1);
    asm volatile("s_waitcnt vmcnt(9)" ::: "memory");   // tile 0 landed
    __builtin_amdgcn_s_barrier();

    int cur = 0;
    for (int tt=0; tt<NTILE; ++tt){
        if (tt+2 < NTILE){
            int ib = cur+2; if (ib>=3) ib-=3;
            issue_tile(tt+2, ib);                       // 2 tiles in flight
        }

        // ---- transpose Kf[cur] (d<512) -> Vt bf16
        {
            const int kg = tid&1;
            const int dq = tid>>1;           // granule 0..127, d0 = dq*4
            float4 rv[8];
#pragma unroll
            for (int i=0;i<8;++i){
                int r = kg*8 + i;
                rv[i] = *(const float4*)(&Kf[cur][r*576 + ((dq ^ (r&7))<<2)]);
            }
#pragma unroll
            for (int j=0;j<4;++j){
                const float* f0 = (const float*)&rv[0];
                const float* f1 = (const float*)&rv[1];
                const float* f2 = (const float*)&rv[2];
                const float* f3 = (const float*)&rv[3];
                const float* f4 = (const float*)&rv[4];
                const float* f5 = (const float*)&rv[5];
                const float* f6 = (const float*)&rv[6];
                const float* f7 = (const float*)&rv[7];
                uint4 o;
                o.x = pack2(f0[j], f1[j]); o.y = pack2(f2[j], f3[j]);
                o.z = pack2(f4[j], f5[j]); o.w = pack2(f6[j], f7[j]);
                *(uint4*)(Vt + vt_addr(dq*4+j, kg*8)) = o;
            }
        }
        // ---- QK^T partial (convert K rows from fp32 LDS on the fly)
        {
            f32x4 sacc; sacc[0]=0.f; sacc[1]=0.f; sacc[2]=0.f; sacc[3]=0.f;
            const float* kb = &Kf[cur][lm*576];
            const int sw = lm&7;
            __builtin_amdgcn_s_setprio(1);
#pragma unroll
            for (int ss=0;ss<9;++ss){
                int g = dh*72 + ss*8 + lg*2;
                float4 fa = *(const float4*)(kb + ((g ^ sw)<<2));
                float4 fb = *(const float4*)(kb + (((g+1) ^ sw)<<2));
                union{uint4 u; bf16x8 v;} cv;
                cv.u.x = pack2(fa.x, fa.y); cv.u.y = pack2(fa.z, fa.w);
                cv.u.z = pack2(fb.x, fb.y); cv.u.w = pack2(fb.z, fb.w);
                sacc = __builtin_amdgcn_mfma_f32_16x16x32_bf16(qf[ss], cv.v, sacc, 0,0,0);
            }
            __builtin_amdgcn_s_setprio(0);
#pragma unroll
            for (int r=0;r<4;++r) S_s[dh][ht*16 + (lg<<2) + r][lm] = sacc[r];
        }
        LGKM_BARRIER();                    // #1 (vmcnt NOT drained)

        // ---- online softmax
        {
            const int kbase = k0 + tt*TK;
            float sc[2];
#pragma unroll
            for (int j=0;j<2;++j){
                int k = s5 + 8*j;
                float v = (S_s[0][myh][k] + S_s[1][myh][k])*SM_SCALE;
                sc[j] = (kbase + k < seqlen) ? v : NEGINF;
            }
            float tmax = fmaxf(sc[0],sc[1]);
            tmax = fmaxf(tmax, __shfl_xor(tmax,1));
            tmax = fmaxf(tmax, __shfl_xor(tmax,2));
            tmax = fmaxf(tmax, __shfl_xor(tmax,4));
            float mnew = fmaxf(m_run, tmax);
            float al = __expf(m_run - mnew);
            float ps = 0.f;
#pragma unroll
            for (int j=0;j<2;++j){
                float pv = (sc[j] > 0.5f*NEGINF) ? __expf(sc[j]-mnew) : 0.f;
                ps += pv;
                P_s[myh][s5 + 8*j] = f2bf(pv);
            }
            ps += __shfl_xor(ps,1); ps += __shfl_xor(ps,2); ps += __shfl_xor(ps,4);
            l_run = l_run*al + ps;
            m_run = mnew;
            if (s5==0) alpha_s[myh] = al;
        }
        LGKM_BARRIER();                    // #2

        // ---- PV
        {
            float al4[4];
#pragma unroll
            for (int r=0;r<4;++r) al4[r] = alpha_s[ht*16 + (lg<<2) + r];
            bf16x8 pa = *(const bf16x8*)(&P_s[ht*16+lm][lg*8]);
            __builtin_amdgcn_s_setprio(1);
#pragma unroll
            for (int nt=0;nt<16;++nt){
                f32x4 o = oacc[nt];
                o[0]*=al4[0]; o[1]*=al4[1]; o[2]*=al4[2]; o[3]*=al4[3];
                int r = dh*256 + nt*16 + lm;
                bf16x8 bv = *(const bf16x8*)(Vt + vt_addr(r, (lg&1)*8));
                oacc[nt] = __builtin_amdgcn_mfma_f32_16x16x32_bf16(pa, bv, o, 0,0,0);
            }
            __builtin_amdgcn_s_setprio(0);
        }
        // ---- tail: wait next tile's DMA (counted — tile t+2 stays in flight)
        if (tt+2 < NTILE){
            asm volatile("s_waitcnt vmcnt(9)" ::: "memory");
            __builtin_amdgcn_s_barrier();
        } else if (tt+1 < NTILE){
            asm volatile("s_waitcnt vmcnt(0)" ::: "memory");
            __builtin_amdgcn_s_barrier();
        }
        cur = cur+1; if (cur>=3) cur-=3;
    }

    const int obase = (b*NSPLIT+sp)*32;
#pragma unroll
    for (int nt=0;nt<16;++nt){
        int r = dh*256 + nt*16 + lm;
#pragma unroll
        for (int qq=0;qq<4;++qq){
            int h = ht*16 + (lg<<2) + qq;
            Opart[((size_t)(obase+h))*512 + r] = oacc[nt][qq];
        }
    }
    if (s5==0){ Mpart[obase+myh]=m_run; Lpart[obase+myh]=l_run; }
}

// ---------- av_uv via MFMA with fused split-merge + fused hi/lo pack of ao
__global__ __launch_bounds__(256) void av_uv_merge(const float* __restrict__ Opart,
        const float* __restrict__ Mpart, const float* __restrict__ Lpart,
        const float* __restrict__ wuv,
        unsigned short* __restrict__ Hi, unsigned short* __restrict__ Lo)
{
    __shared__ unsigned short Bh[4096], Bl[4096];
    __shared__ float lwn[64][4];
    const int h = blockIdx.x;
    const int tid = threadIdx.x;
    const int w = tid>>6, l = tid&63, lm = l&15, lg = l>>4;

    if (tid < 64){
        int b = tid;
        float m0 = Mpart[(b*NSPLIT+0)*32+h], m1 = Mpart[(b*NSPLIT+1)*32+h];
        float m2 = Mpart[(b*NSPLIT+2)*32+h], m3 = Mpart[(b*NSPLIT+3)*32+h];
        float M = fmaxf(fmaxf(m0,m1),fmaxf(m2,m3));
        float w0 = __expf(m0-M), w1 = __expf(m1-M), w2 = __expf(m2-M), w3 = __expf(m3-M);
        float L = w0*Lpart[(b*NSPLIT+0)*32+h] + w1*Lpart[(b*NSPLIT+1)*32+h]
                + w2*Lpart[(b*NSPLIT+2)*32+h] + w3*Lpart[(b*NSPLIT+3)*32+h];
        float inv = 1.f/L;
        lwn[b][0]=w0*inv; lwn[b][1]=w1*inv; lwn[b][2]=w2*inv; lwn[b][3]=w3*inv;
    }
    __syncthreads();

    f32x4 acc[8];
#pragma unroll
    for (int i=0;i<8;++i){ acc[i][0]=0.f; acc[i][1]=0.f; acc[i][2]=0.f; acc[i][3]=0.f; }

    for (int ck=0; ck<16; ++ck){
        const int k0 = ck*32;
        unsigned short hh[2][8], ll[2][8]; int wid0 = tid*2;
#pragma unroll
        for (int wi=0; wi<2; ++wi){
            int wid = wid0 + wi;
            int ntile = wid>>6, kg = (wid>>4)&3, nl = wid&15;
            int n = ntile*16 + nl;
            const float* wp = wuv + (size_t)h*65536 + (size_t)(k0+kg*8)*128 + n;
#pragma unroll
            for (int j=0;j<8;++j){
                float v = wp[(size_t)j*128];
                hh[wi][j] = f2bf(v);
                ll[wi][j] = f2bf(v - bf2f(hh[wi][j]));
            }
        }
        __syncthreads();
#pragma unroll
        for (int wi=0; wi<2; ++wi){
            int wid = wid0 + wi;
            uint4 uh, ul;
            uh.x=(unsigned)hh[wi][0]|((unsigned)hh[wi][1]<<16); uh.y=(unsigned)hh[wi][2]|((unsigned)hh[wi][3]<<16);
            uh.z=(unsigned)hh[wi][4]|((unsigned)hh[wi][5]<<16); uh.w=(unsigned)hh[wi][6]|((unsigned)hh[wi][7]<<16);
            ul.x=(unsigned)ll[wi][0]|((unsigned)ll[wi][1]<<16); ul.y=(unsigned)ll[wi][2]|((unsigned)ll[wi][3]<<16);
            ul.z=(unsigned)ll[wi][4]|((unsigned)ll[wi][5]<<16); ul.w=(unsigned)ll[wi][6]|((unsigned)ll[wi][7]<<16);
            *(uint4*)(Bh + wid*8) = uh;
            *(uint4*)(Bl + wid*8) = ul;
        }
        __syncthreads();
        const int bb = w*16 + lm;
        // A = merged attn row: sum_s lwn[bb][s]*Opart[((bb*4+s)*32+h)*512 + k]
        const float* op = Opart + (((size_t)bb*NSPLIT)*32 + h)*512 + k0 + lg*8;
        float l0=lwn[bb][0], l1=lwn[bb][1], l2=lwn[bb][2], l3=lwn[bb][3];
        float4 s0a = *(const float4*)(op);          float4 s0b = *(const float4*)(op+4);
        float4 s1a = *(const float4*)(op+16384);    float4 s1b = *(const float4*)(op+16388);
        float4 s2a = *(const float4*)(op+32768);    float4 s2b = *(const float4*)(op+32772);
        float4 s3a = *(const float4*)(op+49152);    float4 s3b = *(const float4*)(op+49156);
        float a[8];
        a[0]=l0*s0a.x+l1*s1a.x+l2*s2a.x+l3*s3a.x;
        a[1]=l0*s0a.y+l1*s1a.y+l2*s2a.y+l3*s3a.y;
        a[2]=l0*s0a.z+l1*s1a.z+l2*s2a.z+l3*s3a.z;
        a[3]=l0*s0a.w+l1*s1a.w+l2*s2a.w+l3*s3a.w;
        a[4]=l0*s0b.x+l1*s1b.x+l2*s2b.x+l3*s3b.x;
        a[5]=l0*s0b.y+l1*s1b.y+l2*s2b.y+l3*s3b.y;
        a[6]=l0*s0b.z+l1*s1b.z+l2*s2b.z+l3*s3b.z;
        a[7]=l0*s0b.w+l1*s1b.w+l2*s2b.w+l3*s3b.w;
        union{uint4 u; bf16x8 v;} fh, fl;
        unsigned short hsv[8], lsv[8];
#pragma unroll
        for (int j=0;j<8;++j){ hsv[j]=f2bf(a[j]); lsv[j]=f2bf(a[j]-bf2f(hsv[j])); }
        fh.u.x=(unsigned)hsv[0]|((unsigned)hsv[1]<<16); fh.u.y=(unsigned)hsv[2]|((unsigned)hsv[3]<<16);
        fh.u.z=(unsigned)hsv[4]|((unsigned)hsv[5]<<16); fh.u.w=(unsigned)hsv[6]|((unsigned)hsv[7]<<16);
        fl.u.x=(unsigned)lsv[0]|((unsigned)lsv[1]<<16); fl.u.y=(unsigned)lsv[2]|((unsigned)lsv[3]<<16);
        fl.u.z=(unsigned)lsv[4]|((unsigned)lsv[5]<<16); fl.u.w=(unsigned)lsv[6]|((unsigned)lsv[7]<<16);
#pragma unroll
        for (int nt=0;nt<8;++nt){
            const int fb = (nt*64 + lg*16 + lm)*8;
            bf16x8 fbh = *(const bf16x8*)(Bh + fb);
            bf16x8 fbl = *(const bf16x8*)(Bl + fb);
            acc[nt] = __builtin_amdgcn_mfma_f32_16x16x32_bf16(fh.v, fbh, acc[nt], 0,0,0);
            acc[nt] = __builtin_amdgcn_mfma_f32_16x16x32_bf16(fl.v, fbh, acc[nt], 0,0,0);
            acc[nt] = __builtin_amdgcn_mfma_f32_16x16x32_bf16(fh.v, fbl, acc[nt], 0,0,0);
        }
        __syncthreads();
    }
#pragma unroll
    for (int nt=0;nt<8;++nt){
#pragma unroll
        for (int qq=0;qq<4;++qq){
            float val = acc[nt][qq];
            int bb = w*16 + lg*4 + qq;
            int k = h*128 + nt*16 + lm;
            unsigned short hv = f2bf(val);
            unsigned short lv = f2bf(val - bf2f(hv));
            size_t ui = (size_t)(k>>3)*512 + bb*8 + (k&7);
            Hi[ui] = hv; Lo[ui] = lv;
        }
    }
}

extern "C" void kernel_launch(void* const* d_in, const int* in_sizes, int n_in,
                              void* d_out, int out_size, void* d_ws, size_t ws_size,
                              hipStream_t stream)
{
    const float* hidden = (const float*)d_in[0];
    const float* cosb   = (const float*)d_in[1];
    const float* sinb   = (const float*)d_in[2];
    const float* kv     = (const float*)d_in[3];
    const float* w_q_a  = (const float*)d_in[4];
    const float* q_ln   = (const float*)d_in[5];
    const float* w_q_b  = (const float*)d_in[6];
    const float* w_kv_a = (const float*)d_in[7];
    const float* kv_ln  = (const float*)d_in[8];
    const float* w_uk_t = (const float*)d_in[9];
    const float* w_uv   = (const float*)d_in[10];
    const float* w_o    = (const float*)d_in[11];
    const int* slots    = (const int*)d_in[12];
    const int* seqlens  = (const int*)d_in[13];
    float* out = (float*)d_out;

    float* W = (float*)d_ws;
    float* P0     = W;                   // 4,194,304 (Opart / wqa parts / wqb parts / wo parts)
    float* P1     = W + 4194304;         // 2,097,152 (wkva parts)
    float* q      = W + 6291456;         // 393,216
    float* query  = W + 6684672;         // 1,179,648
    float* latent = W + 7864320;         // 36,864
    float* Mp     = W + 7901184;         // 8,192
    float* Lp     = W + 7909376;         // 8,192
    unsigned short* pkhid_h = (unsigned short*)(W + 7917568);   // 229,376 f32 each
    unsigned short* pkhid_l = (unsigned short*)(W + 8146944);
    unsigned short* pkqc_h  = (unsigned short*)(W + 8376320);   // 49,152 f32 each
    unsigned short* pkqc_l  = (unsigned short*)(W + 8425472);
    unsigned short* pkao_h  = (unsigned short*)(W + 8474624);   // 131,072 f32 each
    unsigned short* pkao_l  = (unsigned short*)(W + 8605696);   // end 8,736,768

    hipLaunchKernelGGL(pack_a, dim3(224), dim3(256), 0, stream, hidden, pkhid_h, pkhid_l, 7168);
    // w_q_a (24x28) || w_kv_a (9x56) in one launch
    hipLaunchKernelGGL(gemm_dual, dim3(672+504), dim3(256), 0, stream,
                       pkhid_h, pkhid_l, w_q_a, P0, 1536, 8, 24, 672, w_kv_a, P1, 576, 4, 9);
    // rms_qc_pack || reduce_kv_rope
    hipLaunchKernelGGL(norm_dual, dim3(128), dim3(256), 0, stream,
                       P0, q_ln, pkqc_h, pkqc_l, 28, P1, kv_ln, cosb, sinb, latent, 56);
    hipLaunchKernelGGL(gemm_mfma, dim3(96,6), dim3(256), 0, stream, pkqc_h, pkqc_l, w_q_b, P0, 6144, 8);
    hipLaunchKernelGGL(finish_q, dim3(1536), dim3(256), 0, stream, P0, cosb, sinb, q, query, 6);
    hipLaunchKernelGGL(qlnope_mfma, dim3(32,4), dim3(256), 0, stream, q, w_uk_t, query);
    hipLaunchKernelGGL(attn_mfma, dim3(NSPLIT,64), dim3(256), 0, stream,
                       query, kv, latent, slots, seqlens, P0, Mp, Lp);
    hipLaunchKernelGGL(av_uv_merge, dim3(32), dim3(256), 0, stream, P0, Mp, Lp, w_uv, pkao_h, pkao_l);
    hipLaunchKernelGGL(gemm_mfma, dim3(112,8), dim3(256), 0, stream, pkao_h, pkao_l, w_o, P0, 7168, 16);
    hipLaunchKernelGGL(reduce_sum, dim3(1792), dim3(256), 0, stream, P0, out, 8, 7168);
}

// Round 10
// 332.634 us; speedup vs baseline: 2.4747x; 1.1656x over previous
//
#include <hip/hip_runtime.h>
#include <stdint.h>

#define NB 64
#define NH 32
#define KCTX 4096
#define HID 7168
#define QLORA 1536
#define KVL 512
#define DTOT 576
#define NSPLIT 4
#define KSPAN 1024
#define NTILE 64           // KSPAN/16
#define TK 16
#define SM_SCALE 0.07216878364870323f  // 1/sqrt(192)
#define NEGINF (-3.0e38f)

typedef __attribute__((ext_vector_type(4))) float f32x4;
typedef __attribute__((ext_vector_type(8))) __bf16 bf16x8;

#define LGKM_BARRIER() do{ asm volatile("s_waitcnt lgkmcnt(0)" ::: "memory"); __builtin_amdgcn_s_barrier(); } while(0)

static __device__ __forceinline__ void glds16(const void* g, void* s){
    __builtin_amdgcn_global_load_lds((const __attribute__((address_space(1))) void*)g,
                                     (__attribute__((address_space(3))) void*)s, 16, 0, 0);
}

static __device__ __forceinline__ unsigned short f2bf(float f){
    union{__bf16 h; unsigned short s;} x; x.h = (__bf16)f; return x.s;
}
static __device__ __forceinline__ float bf2f(unsigned short h){
    union{unsigned i;float f;}x; x.i=((unsigned)h)<<16; return x.f;
}
static __device__ __forceinline__ unsigned pack2(float a, float b){
    union{__bf16 h[2]; unsigned u;} x; x.h[0]=(__bf16)a; x.h[1]=(__bf16)b; return x.u;
}

// ---------- pack A[64][K] fp32 -> frag-ready bf16 hi/lo words: word idx = (k>>3)*64+m
__global__ __launch_bounds__(256) void pack_a(const float* __restrict__ A,
        unsigned short* __restrict__ Hi, unsigned short* __restrict__ Lo, int K)
{
    int idx = blockIdx.x*256 + threadIdx.x;
    int m = idx & 63, kb = idx >> 6;
    const float* src = A + (size_t)m*K + kb*8;
    float v[8];
    *(float4*)(v)   = *(const float4*)(src);
    *(float4*)(v+4) = *(const float4*)(src+4);
    unsigned short h[8], l[8];
#pragma unroll
    for (int j=0;j<8;++j){
        h[j] = f2bf(v[j]);
        l[j] = f2bf(v[j] - bf2f(h[j]));
    }
    uint4 uh, ul;
    uh.x=(unsigned)h[0]|((unsigned)h[1]<<16); uh.y=(unsigned)h[2]|((unsigned)h[3]<<16);
    uh.z=(unsigned)h[4]|((unsigned)h[5]<<16); uh.w=(unsigned)h[6]|((unsigned)h[7]<<16);
    ul.x=(unsigned)l[0]|((unsigned)l[1]<<16); ul.y=(unsigned)l[2]|((unsigned)l[3]<<16);
    ul.z=(unsigned)l[4]|((unsigned)l[5]<<16); ul.w=(unsigned)l[6]|((unsigned)l[7]<<16);
    *(uint4*)(Hi + (size_t)idx*8) = uh;
    *(uint4*)(Lo + (size_t)idx*8) = ul;
}

// ---------- shared MFMA skinny-GEMM core (double-buffered LDS, 1 barrier/step)
static __device__ __forceinline__ void gemm_core(
        const unsigned short* __restrict__ Ahi, const unsigned short* __restrict__ Alo,
        const float* __restrict__ Wm, float* __restrict__ P, int N, int ksteps,
        int bx, int by,
        unsigned short* Ah, unsigned short* Al, unsigned short* Bh, unsigned short* Bl)
{
    const int tid = threadIdx.x;
    const int w = tid>>6, l = tid&63, lm = l&15, lg = l>>4;
    const int n0 = bx*64;
    const int s  = by;
    const int mn = tid&63, ks = tid>>6;
    const int widx = ((mn>>4)*64 + ks*16 + (mn&15));

    f32x4 acc[4];
#pragma unroll
    for (int i=0;i<4;++i){ acc[i][0]=0.f; acc[i][1]=0.f; acc[i][2]=0.f; acc[i][3]=0.f; }

    uint4 ah4, al4; float wv[8];
    auto load_raw = [&](int t){
        const int k0 = (s*ksteps + t)*32;
        size_t gidx = (size_t)((k0>>3) + ks)*64 + mn;
        ah4 = *(const uint4*)(Ahi + gidx*8);
        al4 = *(const uint4*)(Alo + gidx*8);
        const float* wp = Wm + (size_t)(k0 + ks*8)*N + n0 + mn;
#pragma unroll
        for (int j=0;j<8;++j) wv[j] = wp[(size_t)j*N];
    };
    auto cvt_write = [&](int buf){
        unsigned short h[8], lo[8];
#pragma unroll
        for (int j=0;j<8;++j){
            h[j]  = f2bf(wv[j]);
            lo[j] = f2bf(wv[j] - bf2f(h[j]));
        }
        uint4 bh4, bl4;
        bh4.x=(unsigned)h[0]|((unsigned)h[1]<<16); bh4.y=(unsigned)h[2]|((unsigned)h[3]<<16);
        bh4.z=(unsigned)h[4]|((unsigned)h[5]<<16); bh4.w=(unsigned)h[6]|((unsigned)h[7]<<16);
        bl4.x=(unsigned)lo[0]|((unsigned)lo[1]<<16); bl4.y=(unsigned)lo[2]|((unsigned)lo[3]<<16);
        bl4.z=(unsigned)lo[4]|((unsigned)lo[5]<<16); bl4.w=(unsigned)lo[6]|((unsigned)lo[7]<<16);
        *(uint4*)(Ah + buf*2048 + widx*8) = ah4;
        *(uint4*)(Al + buf*2048 + widx*8) = al4;
        *(uint4*)(Bh + buf*2048 + widx*8) = bh4;
        *(uint4*)(Bl + buf*2048 + widx*8) = bl4;
    };

    load_raw(0);
    for (int t=0; t<ksteps; ++t){
        const int buf = t&1;
        cvt_write(buf);
        __syncthreads();
        if (t+1 < ksteps) load_raw(t+1);
        const int fa = buf*2048 + (w*64 + lg*16 + lm)*8;
        bf16x8 fah = *(const bf16x8*)(Ah + fa);
        bf16x8 fal = *(const bf16x8*)(Al + fa);
#pragma unroll
        for (int nt=0;nt<4;++nt){
            const int fb = buf*2048 + (nt*64 + lg*16 + lm)*8;
            bf16x8 fbh = *(const bf16x8*)(Bh + fb);
            bf16x8 fbl = *(const bf16x8*)(Bl + fb);
            acc[nt] = __builtin_amdgcn_mfma_f32_16x16x32_bf16(fah, fbh, acc[nt], 0,0,0);
            acc[nt] = __builtin_amdgcn_mfma_f32_16x16x32_bf16(fal, fbh, acc[nt], 0,0,0);
            acc[nt] = __builtin_amdgcn_mfma_f32_16x16x32_bf16(fah, fbl, acc[nt], 0,0,0);
        }
        __syncthreads();
    }
#pragma unroll
    for (int nt=0;nt<4;++nt){
        int n = n0 + nt*16 + lm;
#pragma unroll
        for (int r=0;r<4;++r){
            int m = w*16 + lg*4 + r;
            P[((size_t)s*64 + m)*N + n] = acc[nt][r];
        }
    }
}

__global__ __launch_bounds__(256) void gemm_mfma(
        const unsigned short* __restrict__ Ahi, const unsigned short* __restrict__ Alo,
        const float* __restrict__ Wm, float* __restrict__ P, int N, int ksteps)
{
    __shared__ unsigned short Ah[2*2048], Al[2*2048], Bh[2*2048], Bl[2*2048];
    gemm_core(Ahi, Alo, Wm, P, N, ksteps, blockIdx.x, blockIdx.y, Ah, Al, Bh, Bl);
}

// two independent GEMMs in one launch (w_q_a || w_kv_a)
__global__ __launch_bounds__(256) void gemm_dual(
        const unsigned short* __restrict__ Ahi, const unsigned short* __restrict__ Alo,
        const float* __restrict__ W0, float* __restrict__ P0, int N0, int ks0, int nbx0, int nblk0,
        const float* __restrict__ W1, float* __restrict__ P1, int N1, int ks1, int nbx1)
{
    __shared__ unsigned short Ah[2*2048], Al[2*2048], Bh[2*2048], Bl[2*2048];
    int bid = blockIdx.x;
    if (bid < nblk0){
        gemm_core(Ahi, Alo, W0, P0, N0, ks0, bid%nbx0, bid/nbx0, Ah, Al, Bh, Bl);
    } else {
        bid -= nblk0;
        gemm_core(Ahi, Alo, W1, P1, N1, ks1, bid%nbx1, bid/nbx1, Ah, Al, Bh, Bl);
    }
}

// ---------- rms_qc_pack core
static __device__ __forceinline__ void rms_core(const float* __restrict__ P,
        const float* __restrict__ w, unsigned short* __restrict__ Hi,
        unsigned short* __restrict__ Lo, int S, int b, float* red)
{
    const int t = threadIdx.x;
    float v[6]; float ss = 0.f;
#pragma unroll
    for (int j=0;j<6;++j){
        int n = j*256 + t;
        float s = 0.f;
        for (int sp=0; sp<S; ++sp) s += P[((size_t)sp*64+b)*1536 + n];
        v[j] = s; ss += s*s;
    }
#pragma unroll
    for (int off=32; off>=1; off>>=1) ss += __shfl_xor(ss, off, 64);
    if ((t&63)==0) red[t>>6] = ss;
    __syncthreads();
    float tot = red[0]+red[1]+red[2]+red[3];
    float rs = rsqrtf(tot/1536.f + 1e-6f);
#pragma unroll
    for (int j=0;j<6;++j){
        int n = j*256+t;
        float val = v[j]*rs*w[n];
        unsigned short hs = f2bf(val);
        unsigned short ls = f2bf(val - bf2f(hs));
        size_t ui = (size_t)(n>>3)*512 + b*8 + (n&7);
        Hi[ui] = hs; Lo[ui] = ls;
    }
}

// ---------- reduce_kv_rope core
static __device__ __forceinline__ void kvrope_core(const float* __restrict__ P,
        const float* __restrict__ w, const float* __restrict__ cosb, const float* __restrict__ sinb,
        float* __restrict__ latent, int S, int b, float* vals, float* red)
{
    const int t = threadIdx.x;
    float ss = 0.f;
    for (int j=0;j<3;++j){
        int n = j*256+t;
        if (n < 576){
            float s=0.f;
            for (int sp=0;sp<S;++sp) s += P[((size_t)sp*64+b)*576 + n];
            vals[n]=s;
            if (n<512) ss += s*s;
        }
    }
#pragma unroll
    for (int off=32; off>=1; off>>=1) ss += __shfl_xor(ss, off, 64);
    if ((t&63)==0) red[t>>6]=ss;
    __syncthreads();
    float tot = red[0]+red[1]+red[2]+red[3];
    float rs = rsqrtf(tot/512.f + 1e-6f);
    for (int j=0;j<3;++j){
        int n = j*256+t;
        if (n<576){
            float o;
            if (n < 512) o = vals[n]*rs*w[n];
            else if (n < 544){ int i=n-512; o = vals[512+2*i]*cosb[b*32+i] - vals[513+2*i]*sinb[b*32+i]; }
            else            { int i=n-544; o = vals[513+2*i]*cosb[b*32+i] + vals[512+2*i]*sinb[b*32+i]; }
            latent[(size_t)b*576 + n] = o;
        }
    }
}

// rms_qc_pack || reduce_kv_rope in one launch
__global__ __launch_bounds__(256) void norm_dual(
        const float* __restrict__ Pq, const float* __restrict__ qw,
        unsigned short* __restrict__ Hi, unsigned short* __restrict__ Lo, int Sq,
        const float* __restrict__ Pkv, const float* __restrict__ kvw,
        const float* __restrict__ cosb, const float* __restrict__ sinb,
        float* __restrict__ latent, int Skv)
{
    __shared__ float vals[576];
    __shared__ float red[4];
    if (blockIdx.x < 64) rms_core(Pq, qw, Hi, Lo, Sq, blockIdx.x, red);
    else                 kvrope_core(Pkv, kvw, cosb, sinb, latent, Skv, blockIdx.x-64, vals, red);
}

// ---------- generic partial reduce
__global__ __launch_bounds__(256) void reduce_sum(const float* __restrict__ P,
        float* __restrict__ out, int S, int N)
{
    int i = blockIdx.x*256 + threadIdx.x;
    int b = i / N, n = i - b*N;
    float s = 0.f;
    for (int sp=0; sp<S; ++sp) s += P[((size_t)sp*64+b)*N + n];
    out[i] = s;
}

// ---------- finish q: reduce partials; n<128 -> q fp32; rope -> query[512..]
__global__ __launch_bounds__(256) void finish_q(const float* __restrict__ P,
        const float* __restrict__ cosb, const float* __restrict__ sinb,
        float* __restrict__ q, float* __restrict__ query, int S)
{
    int i = blockIdx.x*256 + threadIdx.x;
    int b = i / 6144, n = i - b*6144;
    float s = 0.f;
    for (int sp=0; sp<S; ++sp) s += P[((size_t)sp*64+b)*6144 + n];
    int h = n/192, nl = n - h*192;
    if (nl < 128){
        q[((size_t)b*32+h)*192 + nl] = s;
    } else {
        int i2 = (nl-128)>>1;
        float other = __shfl_xor(s, 1);
        float c = cosb[b*32+i2], sn = sinb[b*32+i2];
        float* o = query + ((size_t)b*32+h)*576;
        if ((nl&1)==0) o[512+i2] = s*c - other*sn;
        else           o[544+i2] = s*c + other*sn;
    }
}

// ---------- ql_nope via MFMA
__global__ __launch_bounds__(256) void qlnope_mfma(const float* __restrict__ q,
        const float* __restrict__ wukt, float* __restrict__ query)
{
    __shared__ unsigned short Bh[4096], Bl[4096];
    const int h = blockIdx.x, r0 = blockIdx.y*128;
    const int tid = threadIdx.x;
    const int w = tid>>6, l = tid&63, lm = l&15, lg = l>>4;
    f32x4 acc[8];
#pragma unroll
    for (int i=0;i<8;++i){ acc[i][0]=0.f; acc[i][1]=0.f; acc[i][2]=0.f; acc[i][3]=0.f; }

    for (int ck=0; ck<4; ++ck){
        const int k0 = ck*32;
        unsigned short hh[2][8], ll[2][8]; int wid0 = tid*2;
#pragma unroll
        for (int wi=0; wi<2; ++wi){
            int wid = wid0 + wi;
            int ntile = wid>>6, kg = (wid>>4)&3, nl = wid&15;
            int n = r0 + ntile*16 + nl;
            const float* wp = wukt + (size_t)h*65536 + (size_t)(k0+kg*8)*512 + n;
#pragma unroll
            for (int j=0;j<8;++j){
                float v = wp[(size_t)j*512];
                hh[wi][j] = f2bf(v);
                ll[wi][j] = f2bf(v - bf2f(hh[wi][j]));
            }
        }
        __syncthreads();
#pragma unroll
        for (int wi=0; wi<2; ++wi){
            int wid = wid0 + wi;
            uint4 uh, ul;
            uh.x=(unsigned)hh[wi][0]|((unsigned)hh[wi][1]<<16); uh.y=(unsigned)hh[wi][2]|((unsigned)hh[wi][3]<<16);
            uh.z=(unsigned)hh[wi][4]|((unsigned)hh[wi][5]<<16); uh.w=(unsigned)hh[wi][6]|((unsigned)hh[wi][7]<<16);
            ul.x=(unsigned)ll[wi][0]|((unsigned)ll[wi][1]<<16); ul.y=(unsigned)ll[wi][2]|((unsigned)ll[wi][3]<<16);
            ul.z=(unsigned)ll[wi][4]|((unsigned)ll[wi][5]<<16); ul.w=(unsigned)ll[wi][6]|((unsigned)ll[wi][7]<<16);
            *(uint4*)(Bh + wid*8) = uh;
            *(uint4*)(Bl + wid*8) = ul;
        }
        __syncthreads();
        const int bb = w*16 + lm;
        const float* ap = q + ((size_t)bb*32 + h)*192 + k0 + lg*8;
        float4 a0 = *(const float4*)ap;
        float4 a1 = *(const float4*)(ap+4);
        union{uint4 u; bf16x8 v;} fh, fl;
        fh.u.x=pack2(a0.x,a0.y); fh.u.y=pack2(a0.z,a0.w);
        fh.u.z=pack2(a1.x,a1.y); fh.u.w=pack2(a1.z,a1.w);
        float r0f=a0.x-bf2f(f2bf(a0.x)), r1f=a0.y-bf2f(f2bf(a0.y));
        float r2f=a0.z-bf2f(f2bf(a0.z)), r3f=a0.w-bf2f(f2bf(a0.w));
        float r4f=a1.x-bf2f(f2bf(a1.x)), r5f=a1.y-bf2f(f2bf(a1.y));
        float r6f=a1.z-bf2f(f2bf(a1.z)), r7f=a1.w-bf2f(f2bf(a1.w));
        fl.u.x=pack2(r0f,r1f); fl.u.y=pack2(r2f,r3f);
        fl.u.z=pack2(r4f,r5f); fl.u.w=pack2(r6f,r7f);
#pragma unroll
        for (int nt=0;nt<8;++nt){
            const int fb = (nt*64 + lg*16 + lm)*8;
            bf16x8 fbh = *(const bf16x8*)(Bh + fb);
            bf16x8 fbl = *(const bf16x8*)(Bl + fb);
            acc[nt] = __builtin_amdgcn_mfma_f32_16x16x32_bf16(fh.v, fbh, acc[nt], 0,0,0);
            acc[nt] = __builtin_amdgcn_mfma_f32_16x16x32_bf16(fl.v, fbh, acc[nt], 0,0,0);
            acc[nt] = __builtin_amdgcn_mfma_f32_16x16x32_bf16(fh.v, fbl, acc[nt], 0,0,0);
        }
        __syncthreads();
    }
#pragma unroll
    for (int nt=0;nt<8;++nt){
        int r = r0 + nt*16 + lm;
#pragma unroll
        for (int qq=0;qq<4;++qq){
            int bb = w*16 + lg*4 + qq;
            query[((size_t)bb*32 + h)*576 + r] = acc[nt][qq];
        }
    }
}

// Vt flat layout: addr_u16(d,key) = (d>>2)*64 + ((d&3)^((d>>3)&3))*16 + key
static __device__ __forceinline__ int vt_addr(int d, int key){
    return (d>>2)*64 + (((d&3)^((d>>3)&3))<<4) + key;
}

// ---------- flash decode attention v7: 512 threads (2 waves/SIMD), triple-buffer DMA,
// counted per-wave vmcnt. 8 waves = 2 h-tiles x 4 {d-groups (QK) / r-quarters (PV)}.
__global__ __launch_bounds__(512,1) void attn_mfma(const float* __restrict__ query,
        const float* __restrict__ kv, const float* __restrict__ latent,
        const int* __restrict__ slots, const int* __restrict__ seq_lens,
        float* __restrict__ Opart, float* __restrict__ Mpart, float* __restrict__ Lpart)
{
    __shared__ float Kf[3][16*576];               // 110592 B
    __shared__ unsigned short Vt[8192];           // 16384 B
    __shared__ float S_s[4][32][16];              // 8192 B
    __shared__ unsigned short P_s[32][40];        // 2560 B (cols 16..31 zero)
    __shared__ float alpha_s[32];                 // 128 B  -> total 137856 B

    const int b = blockIdx.y, sp = blockIdx.x;
    const int tid = threadIdx.x;
    const int w = tid>>6, l = tid&63;
    const int lm = l&15, lg = l>>4;
    const int ht = w&1;                  // h-tile
    const int dg = w>>1;                 // QK d-group / PV r-quarter
    const int cs = dg*5 - (dg>0?1:0);    // chunk starts {0,4,9,14}
    const int cnt = (dg==1||dg==2)?5:4;
    const int seqlen = seq_lens[b];
    const int slot = slots[b];
    const int k0 = sp*KSPAN;
    const int myh = tid>>4, s5 = tid&15; // softmax: 16 threads/head, 1 key each

    P_s[tid>>4][16 + (tid&15)] = 0;      // zero pad cols 16..31 (512 entries, once each)

    // Q fragments: this wave's (uneven) chunk range; short waves zero-pad qf[4]
    bf16x8 qf[5];
    {
        const float* qrow = query + ((size_t)b*32 + ht*16 + lm)*576;
#pragma unroll
        for (int ss=0;ss<5;++ss){
            if (ss < cnt){
                int d0 = (cs+ss)*32 + lg*8;
                float4 a = *(const float4*)(qrow + d0);
                float4 c = *(const float4*)(qrow + d0 + 4);
                union{uint4 u; bf16x8 v;} cv;
                cv.u.x=pack2(a.x,a.y); cv.u.y=pack2(a.z,a.w);
                cv.u.z=pack2(c.x,c.y); cv.u.w=pack2(c.z,c.w);
                qf[ss]=cv.v;
            } else {
                union{uint4 u; bf16x8 v;} z; z.u.x=0; z.u.y=0; z.u.z=0; z.u.w=0;
                qf[ss]=z.v;
            }
        }
    }

    // DMA stage: 36 glds16/tile, slot s -> wave s&7 (waves 0-3 issue 5, 4-7 issue 4)
    auto issue_tile = [&](int tt, int buf){
        const int gkb = k0 + tt*TK;
#pragma unroll
        for (int i=0;i<5;++i){
            int s = i*8 + w;
            if (s < 36){
                int B = s*1024 + l*16;
                int r = B / 2304;
                int gs = (B - r*2304) >> 4;
                int g  = gs ^ (r&7);
                int gk = gkb + r; if (gk > KCTX-1) gk = KCTX-1;
                const float* src = (gk==slot) ? (latent + (size_t)b*576 + g*4)
                                              : (kv + ((size_t)b*KCTX + gk)*576 + g*4);
                glds16(src, ((char*)&Kf[buf][0]) + B);
            }
        }
    };

    f32x4 oacc[8];
#pragma unroll
    for (int i=0;i<8;++i){ oacc[i][0]=0.f; oacc[i][1]=0.f; oacc[i][2]=0.f; oacc[i][3]=0.f; }
    float m_run = NEGINF, l_run = 0.f;

    issue_tile(0, 0);
    issue_tile(1, 1);
    if (w < 4) { asm volatile("s_waitcnt vmcnt(5)" ::: "memory"); }
    else       { asm volatile("s_waitcnt vmcnt(4)" ::: "memory"); }
    __builtin_amdgcn_s_barrier();

    int cur = 0;
    for (int tt=0; tt<NTILE; ++tt){
        if (tt+2 < NTILE){
            int ib = cur+2; if (ib>=3) ib-=3;
            issue_tile(tt+2, ib);                       // 2 tiles in flight
        }

        // ---- transpose Kf[cur] (d<512) -> Vt bf16 (512 threads, 4 keys x 4 d each)
        {
            const int kg = tid&1;
            const int dq = (tid>>1)&127;
            const int rep = tid>>8;
            float4 rv[4];
#pragma unroll
            for (int i=0;i<4;++i){
                int r = kg*8 + rep*4 + i;
                rv[i] = *(const float4*)(&Kf[cur][r*576 + ((dq ^ (r&7))<<2)]);
            }
#pragma unroll
            for (int j=0;j<4;++j){
                uint2 o;
                o.x = pack2(((const float*)&rv[0])[j], ((const float*)&rv[1])[j]);
                o.y = pack2(((const float*)&rv[2])[j], ((const float*)&rv[3])[j]);
                *(uint2*)(Vt + vt_addr(dq*4+j, kg*8) + rep*4) = o;
            }
        }
        // ---- QK^T partial (this wave's d-group; 5 MFMA, short waves padded)
        {
            f32x4 sacc; sacc[0]=0.f; sacc[1]=0.f; sacc[2]=0.f; sacc[3]=0.f;
            const float* kb = &Kf[cur][lm*576];
            const int sw = lm&7;
            __builtin_amdgcn_s_setprio(1);
#pragma unroll
            for (int ss=0;ss<5;++ss){
                int chunk = cs + (ss<cnt ? ss : 0);
                int g = chunk*8 + lg*2;
                float4 fa = *(const float4*)(kb + ((g ^ sw)<<2));
                float4 fb = *(const float4*)(kb + (((g+1) ^ sw)<<2));
                union{uint4 u; bf16x8 v;} cv;
                cv.u.x = pack2(fa.x, fa.y); cv.u.y = pack2(fa.z, fa.w);
                cv.u.z = pack2(fb.x, fb.y); cv.u.w = pack2(fb.z, fb.w);
                sacc = __builtin_amdgcn_mfma_f32_16x16x32_bf16(qf[ss], cv.v, sacc, 0,0,0);
            }
            __builtin_amdgcn_s_setprio(0);
#pragma unroll
            for (int r=0;r<4;++r) S_s[dg][ht*16 + (lg<<2) + r][lm] = sacc[r];
        }
        LGKM_BARRIER();                    // #1 (vmcnt NOT drained)

        // ---- online softmax: 16 threads/head, 1 key each
        {
            const int kbase = k0 + tt*TK;
            float v = (S_s[0][myh][s5] + S_s[1][myh][s5]
                     + S_s[2][myh][s5] + S_s[3][myh][s5])*SM_SCALE;
            float sc = (kbase + s5 < seqlen) ? v : NEGINF;
            float tmax = sc;
            tmax = fmaxf(tmax, __shfl_xor(tmax,1));
            tmax = fmaxf(tmax, __shfl_xor(tmax,2));
            tmax = fmaxf(tmax, __shfl_xor(tmax,4));
            tmax = fmaxf(tmax, __shfl_xor(tmax,8));
            float mnew = fmaxf(m_run, tmax);
            float al = __expf(m_run - mnew);
            float pv = (sc > 0.5f*NEGINF) ? __expf(sc-mnew) : 0.f;
            P_s[myh][s5] = f2bf(pv);
            float ps = pv;
            ps += __shfl_xor(ps,1); ps += __shfl_xor(ps,2);
            ps += __shfl_xor(ps,4); ps += __shfl_xor(ps,8);
            l_run = l_run*al + ps;
            m_run = mnew;
            if (s5==0) alpha_s[myh] = al;
        }
        LGKM_BARRIER();                    // #2

        // ---- PV: wave (ht, rq=dg): r-range dg*128, 8 n-tiles
        {
            float al4[4];
#pragma unroll
            for (int r=0;r<4;++r) al4[r] = alpha_s[ht*16 + (lg<<2) + r];
            bf16x8 pa = *(const bf16x8*)(&P_s[ht*16+lm][lg*8]);
            __builtin_amdgcn_s_setprio(1);
#pragma unroll
            for (int nt=0;nt<8;++nt){
                f32x4 o = oacc[nt];
                o[0]*=al4[0]; o[1]*=al4[1]; o[2]*=al4[2]; o[3]*=al4[3];
                int r = dg*128 + nt*16 + lm;
                bf16x8 bv = *(const bf16x8*)(Vt + vt_addr(r, (lg&1)*8));
                oacc[nt] = __builtin_amdgcn_mfma_f32_16x16x32_bf16(pa, bv, o, 0,0,0);
            }
            __builtin_amdgcn_s_setprio(0);
        }
        // ---- tail: wait next tile's DMA (counted; tile t+2 stays in flight)
        if (tt+2 < NTILE){
            if (w < 4) { asm volatile("s_waitcnt vmcnt(5)" ::: "memory"); }
            else       { asm volatile("s_waitcnt vmcnt(4)" ::: "memory"); }
            __builtin_amdgcn_s_barrier();
        } else if (tt+1 < NTILE){
            asm volatile("s_waitcnt vmcnt(0)" ::: "memory");
            __builtin_amdgcn_s_barrier();
        }
        cur = cur+1; if (cur>=3) cur-=3;
    }

    const int obase = (b*NSPLIT+sp)*32;
#pragma unroll
    for (int nt=0;nt<8;++nt){
        int r = dg*128 + nt*16 + lm;
#pragma unroll
        for (int qq=0;qq<4;++qq){
            int h = ht*16 + (lg<<2) + qq;
            Opart[((size_t)(obase+h))*512 + r] = oacc[nt][qq];
        }
    }
    if (s5==0){ Mpart[obase+myh]=m_run; Lpart[obase+myh]=l_run; }
}

// ---------- av_uv via MFMA with fused split-merge + fused hi/lo pack of ao
// grid (32 h, 4 bgroup); block = 16 batch rows x 128 v; 4 waves x 2 n-tiles.
__global__ __launch_bounds__(256) void av_uv_merge(const float* __restrict__ Opart,
        const float* __restrict__ Mpart, const float* __restrict__ Lpart,
        const float* __restrict__ wuv,
        unsigned short* __restrict__ Hi, unsigned short* __restrict__ Lo)
{
    __shared__ unsigned short Bh[4096], Bl[4096];
    __shared__ unsigned short Ah[512], Al[512];
    __shared__ float lwn[16][4];
    const int h = blockIdx.x, bg = blockIdx.y;
    const int tid = threadIdx.x;
    const int w = tid>>6, l = tid&63, lm = l&15, lg = l>>4;

    if (tid < 16){
        int b = bg*16 + tid;
        float m0 = Mpart[(b*NSPLIT+0)*32+h], m1 = Mpart[(b*NSPLIT+1)*32+h];
        float m2 = Mpart[(b*NSPLIT+2)*32+h], m3 = Mpart[(b*NSPLIT+3)*32+h];
        float M = fmaxf(fmaxf(m0,m1),fmaxf(m2,m3));
        float w0 = __expf(m0-M), w1 = __expf(m1-M), w2 = __expf(m2-M), w3 = __expf(m3-M);
        float L = w0*Lpart[(b*NSPLIT+0)*32+h] + w1*Lpart[(b*NSPLIT+1)*32+h]
                + w2*Lpart[(b*NSPLIT+2)*32+h] + w3*Lpart[(b*NSPLIT+3)*32+h];
        float inv = 1.f/L;
        lwn[tid][0]=w0*inv; lwn[tid][1]=w1*inv; lwn[tid][2]=w2*inv; lwn[tid][3]=w3*inv;
    }
    __syncthreads();

    f32x4 acc[2];
#pragma unroll
    for (int i=0;i<2;++i){ acc[i][0]=0.f; acc[i][1]=0.f; acc[i][2]=0.f; acc[i][3]=0.f; }

    for (int ck=0; ck<16; ++ck){
        const int k0 = ck*32;
        // B gather (wuv slice): 2 words x 8 scalars
        unsigned short hh[2][8], ll[2][8]; int wid0 = tid*2;
#pragma unroll
        for (int wi=0; wi<2; ++wi){
            int wid = wid0 + wi;
            int ntile = wid>>6, kg = (wid>>4)&3, nl = wid&15;
            int n = ntile*16 + nl;
            const float* wp = wuv + (size_t)h*65536 + (size_t)(k0+kg*8)*128 + n;
#pragma unroll
            for (int j=0;j<8;++j){
                float v = wp[(size_t)j*128];
                hh[wi][j] = f2bf(v);
                ll[wi][j] = f2bf(v - bf2f(hh[wi][j]));
            }
        }
        // A gather: merged attn rows (16 rows x 32 k), 2 elems/thread
        float av[2];
#pragma unroll
        for (int e=0;e<2;++e){
            int id = tid*2+e;
            int row = id>>5, k = id&31;
            int bb = bg*16 + row;
            const float* op = Opart + (((size_t)bb*NSPLIT)*32 + h)*512 + k0 + k;
            av[e] = lwn[row][0]*op[0] + lwn[row][1]*op[16384]
                  + lwn[row][2]*op[32768] + lwn[row][3]*op[49152];
        }
        __syncthreads();
#pragma unroll
        for (int wi=0; wi<2; ++wi){
            int wid = wid0 + wi;
            uint4 uh, ul;
            uh.x=(unsigned)hh[wi][0]|((unsigned)hh[wi][1]<<16); uh.y=(unsigned)hh[wi][2]|((unsigned)hh[wi][3]<<16);
            uh.z=(unsigned)hh[wi][4]|((unsigned)hh[wi][5]<<16); uh.w=(unsigned)hh[wi][6]|((unsigned)hh[wi][7]<<16);
            ul.x=(unsigned)ll[wi][0]|((unsigned)ll[wi][1]<<16); ul.y=(unsigned)ll[wi][2]|((unsigned)ll[wi][3]<<16);
            ul.z=(unsigned)ll[wi][4]|((unsigned)ll[wi][5]<<16); ul.w=(unsigned)ll[wi][6]|((unsigned)ll[wi][7]<<16);
            *(uint4*)(Bh + wid*8) = uh;
            *(uint4*)(Bl + wid*8) = ul;
        }
#pragma unroll
        for (int e=0;e<2;++e){
            int id = tid*2+e;
            int row = id>>5, k = id&31;
            unsigned short hs = f2bf(av[e]);
            unsigned short ls = f2bf(av[e] - bf2f(hs));
            int ai = ((k>>3)*16 + row)*8 + (k&7);
            Ah[ai] = hs; Al[ai] = ls;
        }
        __syncthreads();
        const int fa = (lg*16 + lm)*8;
        bf16x8 fah = *(const bf16x8*)(Ah + fa);
        bf16x8 fal = *(const bf16x8*)(Al + fa);
#pragma unroll
        for (int i=0;i<2;++i){
            int nt = w*2 + i;
            const int fb = (nt*64 + lg*16 + lm)*8;
            bf16x8 fbh = *(const bf16x8*)(Bh + fb);
            bf16x8 fbl = *(const bf16x8*)(Bl + fb);
            acc[i] = __builtin_amdgcn_mfma_f32_16x16x32_bf16(fah, fbh, acc[i], 0,0,0);
            acc[i] = __builtin_amdgcn_mfma_f32_16x16x32_bf16(fal, fbh, acc[i], 0,0,0);
            acc[i] = __builtin_amdgcn_mfma_f32_16x16x32_bf16(fah, fbl, acc[i], 0,0,0);
        }
        __syncthreads();
    }
#pragma unroll
    for (int i=0;i<2;++i){
        int nt = w*2 + i;
#pragma unroll
        for (int qq=0;qq<4;++qq){
            float val = acc[i][qq];
            int bb = bg*16 + lg*4 + qq;
            int k = h*128 + nt*16 + lm;
            unsigned short hv = f2bf(val);
            unsigned short lv = f2bf(val - bf2f(hv));
            size_t ui = (size_t)(k>>3)*512 + bb*8 + (k&7);
            Hi[ui] = hv; Lo[ui] = lv;
        }
    }
}

extern "C" void kernel_launch(void* const* d_in, const int* in_sizes, int n_in,
                              void* d_out, int out_size, void* d_ws, size_t ws_size,
                              hipStream_t stream)
{
    const float* hidden = (const float*)d_in[0];
    const float* cosb   = (const float*)d_in[1];
    const float* sinb   = (const float*)d_in[2];
    const float* kv     = (const float*)d_in[3];
    const float* w_q_a  = (const float*)d_in[4];
    const float* q_ln   = (const float*)d_in[5];
    const float* w_q_b  = (const float*)d_in[6];
    const float* w_kv_a = (const float*)d_in[7];
    const float* kv_ln  = (const float*)d_in[8];
    const float* w_uk_t = (const float*)d_in[9];
    const float* w_uv   = (const float*)d_in[10];
    const float* w_o    = (const float*)d_in[11];
    const int* slots    = (const int*)d_in[12];
    const int* seqlens  = (const int*)d_in[13];
    float* out = (float*)d_out;

    float* W = (float*)d_ws;
    float* P0     = W;                   // 4,194,304 (Opart / wqa parts / wqb parts / wo parts)
    float* P1     = W + 4194304;         // 2,097,152 (wkva parts)
    float* q      = W + 6291456;         // 393,216
    float* query  = W + 6684672;         // 1,179,648
    float* latent = W + 7864320;         // 36,864
    float* Mp     = W + 7901184;         // 8,192
    float* Lp     = W + 7909376;         // 8,192
    unsigned short* pkhid_h = (unsigned short*)(W + 7917568);
    unsigned short* pkhid_l = (unsigned short*)(W + 8146944);
    unsigned short* pkqc_h  = (unsigned short*)(W + 8376320);
    unsigned short* pkqc_l  = (unsigned short*)(W + 8425472);
    unsigned short* pkao_h  = (unsigned short*)(W + 8474624);
    unsigned short* pkao_l  = (unsigned short*)(W + 8605696);

    hipLaunchKernelGGL(pack_a, dim3(224), dim3(256), 0, stream, hidden, pkhid_h, pkhid_l, 7168);
    hipLaunchKernelGGL(gemm_dual, dim3(672+504), dim3(256), 0, stream,
                       pkhid_h, pkhid_l, w_q_a, P0, 1536, 8, 24, 672, w_kv_a, P1, 576, 4, 9);
    hipLaunchKernelGGL(norm_dual, dim3(128), dim3(256), 0, stream,
                       P0, q_ln, pkqc_h, pkqc_l, 28, P1, kv_ln, cosb, sinb, latent, 56);
    hipLaunchKernelGGL(gemm_mfma, dim3(96,6), dim3(256), 0, stream, pkqc_h, pkqc_l, w_q_b, P0, 6144, 8);
    hipLaunchKernelGGL(finish_q, dim3(1536), dim3(256), 0, stream, P0, cosb, sinb, q, query, 6);
    hipLaunchKernelGGL(qlnope_mfma, dim3(32,4), dim3(256), 0, stream, q, w_uk_t, query);
    hipLaunchKernelGGL(attn_mfma, dim3(NSPLIT,64), dim3(512), 0, stream,
                       query, kv, latent, slots, seqlens, P0, Mp, Lp);
    hipLaunchKernelGGL(av_uv_merge, dim3(32,4), dim3(256), 0, stream, P0, Mp, Lp, w_uv, pkao_h, pkao_l);
    hipLaunchKernelGGL(gemm_mfma, dim3(112,8), dim3(256), 0, stream, pkao_h, pkao_l, w_o, P0, 7168, 16);
    hipLaunchKernelGGL(reduce_sum, dim3(1792), dim3(256), 0, stream, P0, out, 8, 7168);
}

// Round 11
// 330.150 us; speedup vs baseline: 2.4934x; 1.0075x over previous
//
#include <hip/hip_runtime.h>
#include <stdint.h>

#define NB 64
#define NH 32
#define KCTX 4096
#define HID 7168
#define QLORA 1536
#define KVL 512
#define DTOT 576
#define NSPLIT 4
#define KSPAN 1024
#define NTILE 64           // KSPAN/16
#define TK 16
#define SM_SCALE 0.07216878364870323f  // 1/sqrt(192)
#define NEGINF (-3.0e38f)

typedef __attribute__((ext_vector_type(4))) float f32x4;
typedef __attribute__((ext_vector_type(8))) __bf16 bf16x8;

#define LGKM_BARRIER() do{ asm volatile("s_waitcnt lgkmcnt(0)" ::: "memory"); __builtin_amdgcn_s_barrier(); } while(0)

static __device__ __forceinline__ void glds16(const void* g, void* s){
    __builtin_amdgcn_global_load_lds((const __attribute__((address_space(1))) void*)g,
                                     (__attribute__((address_space(3))) void*)s, 16, 0, 0);
}

static __device__ __forceinline__ unsigned short f2bf(float f){
    union{__bf16 h; unsigned short s;} x; x.h = (__bf16)f; return x.s;
}
static __device__ __forceinline__ float bf2f(unsigned short h){
    union{unsigned i;float f;}x; x.i=((unsigned)h)<<16; return x.f;
}
static __device__ __forceinline__ unsigned pack2(float a, float b){
    union{__bf16 h[2]; unsigned u;} x; x.h[0]=(__bf16)a; x.h[1]=(__bf16)b; return x.u;
}

// ================= GEMM cores =================
// Epilogue mode: 0 = write partials P[s][m][n]; 1 = unsafeAtomicAdd into Out[m][n]
template<int OUT_MODE>
static __device__ __forceinline__ void gemm_core_packed(
        const unsigned short* __restrict__ Ahi, const unsigned short* __restrict__ Alo,
        const float* __restrict__ Wm, float* __restrict__ P, int N, int ksteps,
        int bx, int by,
        unsigned short* Ah, unsigned short* Al, unsigned short* Bh, unsigned short* Bl)
{
    const int tid = threadIdx.x;
    const int w = tid>>6, l = tid&63, lm = l&15, lg = l>>4;
    const int n0 = bx*64;
    const int s  = by;
    const int mn = tid&63, ks = tid>>6;
    const int widx = ((mn>>4)*64 + ks*16 + (mn&15));

    f32x4 acc[4];
#pragma unroll
    for (int i=0;i<4;++i){ acc[i][0]=0.f; acc[i][1]=0.f; acc[i][2]=0.f; acc[i][3]=0.f; }

    uint4 ah4, al4; float wv[8];
    auto load_raw = [&](int t){
        const int k0 = (s*ksteps + t)*32;
        size_t gidx = (size_t)((k0>>3) + ks)*64 + mn;
        ah4 = *(const uint4*)(Ahi + gidx*8);
        al4 = *(const uint4*)(Alo + gidx*8);
        const float* wp = Wm + (size_t)(k0 + ks*8)*N + n0 + mn;
#pragma unroll
        for (int j=0;j<8;++j) wv[j] = wp[(size_t)j*N];
    };
    auto cvt_write = [&](int buf){
        unsigned short h8[8], l8[8];
#pragma unroll
        for (int j=0;j<8;++j){
            h8[j] = f2bf(wv[j]);
            l8[j] = f2bf(wv[j] - bf2f(h8[j]));
        }
        uint4 bh4, bl4;
        bh4.x=(unsigned)h8[0]|((unsigned)h8[1]<<16); bh4.y=(unsigned)h8[2]|((unsigned)h8[3]<<16);
        bh4.z=(unsigned)h8[4]|((unsigned)h8[5]<<16); bh4.w=(unsigned)h8[6]|((unsigned)h8[7]<<16);
        bl4.x=(unsigned)l8[0]|((unsigned)l8[1]<<16); bl4.y=(unsigned)l8[2]|((unsigned)l8[3]<<16);
        bl4.z=(unsigned)l8[4]|((unsigned)l8[5]<<16); bl4.w=(unsigned)l8[6]|((unsigned)l8[7]<<16);
        *(uint4*)(Ah + buf*2048 + widx*8) = ah4;
        *(uint4*)(Al + buf*2048 + widx*8) = al4;
        *(uint4*)(Bh + buf*2048 + widx*8) = bh4;
        *(uint4*)(Bl + buf*2048 + widx*8) = bl4;
    };

    load_raw(0);
    for (int t=0; t<ksteps; ++t){
        const int buf = t&1;
        cvt_write(buf);
        __syncthreads();
        if (t+1 < ksteps) load_raw(t+1);
        const int fa = buf*2048 + (w*64 + lg*16 + lm)*8;
        bf16x8 fah = *(const bf16x8*)(Ah + fa);
        bf16x8 fal = *(const bf16x8*)(Al + fa);
#pragma unroll
        for (int nt=0;nt<4;++nt){
            const int fb = buf*2048 + (nt*64 + lg*16 + lm)*8;
            bf16x8 fbh = *(const bf16x8*)(Bh + fb);
            bf16x8 fbl = *(const bf16x8*)(Bl + fb);
            acc[nt] = __builtin_amdgcn_mfma_f32_16x16x32_bf16(fah, fbh, acc[nt], 0,0,0);
            acc[nt] = __builtin_amdgcn_mfma_f32_16x16x32_bf16(fal, fbh, acc[nt], 0,0,0);
            acc[nt] = __builtin_amdgcn_mfma_f32_16x16x32_bf16(fah, fbl, acc[nt], 0,0,0);
        }
        __syncthreads();
    }
#pragma unroll
    for (int nt=0;nt<4;++nt){
        int n = n0 + nt*16 + lm;
#pragma unroll
        for (int r=0;r<4;++r){
            int m = w*16 + lg*4 + r;
            if (OUT_MODE == 0) P[((size_t)s*64 + m)*N + n] = acc[nt][r];
            else               unsafeAtomicAdd(&P[(size_t)m*N + n], acc[nt][r]);
        }
    }
}

// raw fp32 A (A[64][KA] row-major), converted in-register
static __device__ __forceinline__ void gemm_core_raw(
        const float* __restrict__ Araw, int KA,
        const float* __restrict__ Wm, float* __restrict__ P, int N, int ksteps,
        int bx, int by,
        unsigned short* Ah, unsigned short* Al, unsigned short* Bh, unsigned short* Bl)
{
    const int tid = threadIdx.x;
    const int w = tid>>6, l = tid&63, lm = l&15, lg = l>>4;
    const int n0 = bx*64;
    const int s  = by;
    const int mn = tid&63, ks = tid>>6;
    const int widx = ((mn>>4)*64 + ks*16 + (mn&15));

    f32x4 acc[4];
#pragma unroll
    for (int i=0;i<4;++i){ acc[i][0]=0.f; acc[i][1]=0.f; acc[i][2]=0.f; acc[i][3]=0.f; }

    float av[8], wv[8];
    auto load_raw = [&](int t){
        const int k0 = (s*ksteps + t)*32;
        const float* ap = Araw + (size_t)mn*KA + k0 + ks*8;
        *(float4*)(av)   = *(const float4*)(ap);
        *(float4*)(av+4) = *(const float4*)(ap+4);
        const float* wp = Wm + (size_t)(k0 + ks*8)*N + n0 + mn;
#pragma unroll
        for (int j=0;j<8;++j) wv[j] = wp[(size_t)j*N];
    };
    auto cvt_write = [&](int buf){
        unsigned short ha[8], la[8], hb[8], lb[8];
#pragma unroll
        for (int j=0;j<8;++j){
            ha[j] = f2bf(av[j]); la[j] = f2bf(av[j] - bf2f(ha[j]));
            hb[j] = f2bf(wv[j]); lb[j] = f2bf(wv[j] - bf2f(hb[j]));
        }
        uint4 ah4, al4, bh4, bl4;
        ah4.x=(unsigned)ha[0]|((unsigned)ha[1]<<16); ah4.y=(unsigned)ha[2]|((unsigned)ha[3]<<16);
        ah4.z=(unsigned)ha[4]|((unsigned)ha[5]<<16); ah4.w=(unsigned)ha[6]|((unsigned)ha[7]<<16);
        al4.x=(unsigned)la[0]|((unsigned)la[1]<<16); al4.y=(unsigned)la[2]|((unsigned)la[3]<<16);
        al4.z=(unsigned)la[4]|((unsigned)la[5]<<16); al4.w=(unsigned)la[6]|((unsigned)la[7]<<16);
        bh4.x=(unsigned)hb[0]|((unsigned)hb[1]<<16); bh4.y=(unsigned)hb[2]|((unsigned)hb[3]<<16);
        bh4.z=(unsigned)hb[4]|((unsigned)hb[5]<<16); bh4.w=(unsigned)hb[6]|((unsigned)hb[7]<<16);
        bl4.x=(unsigned)lb[0]|((unsigned)lb[1]<<16); bl4.y=(unsigned)lb[2]|((unsigned)lb[3]<<16);
        bl4.z=(unsigned)lb[4]|((unsigned)lb[5]<<16); bl4.w=(unsigned)lb[6]|((unsigned)lb[7]<<16);
        *(uint4*)(Ah + buf*2048 + widx*8) = ah4;
        *(uint4*)(Al + buf*2048 + widx*8) = al4;
        *(uint4*)(Bh + buf*2048 + widx*8) = bh4;
        *(uint4*)(Bl + buf*2048 + widx*8) = bl4;
    };

    load_raw(0);
    for (int t=0; t<ksteps; ++t){
        const int buf = t&1;
        cvt_write(buf);
        __syncthreads();
        if (t+1 < ksteps) load_raw(t+1);
        const int fa = buf*2048 + (w*64 + lg*16 + lm)*8;
        bf16x8 fah = *(const bf16x8*)(Ah + fa);
        bf16x8 fal = *(const bf16x8*)(Al + fa);
#pragma unroll
        for (int nt=0;nt<4;++nt){
            const int fb = buf*2048 + (nt*64 + lg*16 + lm)*8;
            bf16x8 fbh = *(const bf16x8*)(Bh + fb);
            bf16x8 fbl = *(const bf16x8*)(Bl + fb);
            acc[nt] = __builtin_amdgcn_mfma_f32_16x16x32_bf16(fah, fbh, acc[nt], 0,0,0);
            acc[nt] = __builtin_amdgcn_mfma_f32_16x16x32_bf16(fal, fbh, acc[nt], 0,0,0);
            acc[nt] = __builtin_amdgcn_mfma_f32_16x16x32_bf16(fah, fbl, acc[nt], 0,0,0);
        }
        __syncthreads();
    }
#pragma unroll
    for (int nt=0;nt<4;++nt){
        int n = n0 + nt*16 + lm;
#pragma unroll
        for (int r=0;r<4;++r){
            int m = w*16 + lg*4 + r;
            P[((size_t)s*64 + m)*N + n] = acc[nt][r];
        }
    }
}

__global__ __launch_bounds__(256) void gemm_mfma(
        const unsigned short* __restrict__ Ahi, const unsigned short* __restrict__ Alo,
        const float* __restrict__ Wm, float* __restrict__ P, int N, int ksteps)
{
    __shared__ unsigned short Ah[2*2048], Al[2*2048], Bh[2*2048], Bl[2*2048];
    gemm_core_packed<0>(Ahi, Alo, Wm, P, N, ksteps, blockIdx.x, blockIdx.y, Ah, Al, Bh, Bl);
}

__global__ __launch_bounds__(256) void gemm_atomic(
        const unsigned short* __restrict__ Ahi, const unsigned short* __restrict__ Alo,
        const float* __restrict__ Wm, float* __restrict__ Out, int N, int ksteps)
{
    __shared__ unsigned short Ah[2*2048], Al[2*2048], Bh[2*2048], Bl[2*2048];
    gemm_core_packed<1>(Ahi, Alo, Wm, Out, N, ksteps, blockIdx.x, blockIdx.y, Ah, Al, Bh, Bl);
}

// two independent raw-A GEMMs in one launch (hidden @ w_q_a || hidden @ w_kv_a)
__global__ __launch_bounds__(256) void gemm_dual_raw(
        const float* __restrict__ Araw, int KA,
        const float* __restrict__ W0, float* __restrict__ P0, int N0, int ks0, int nbx0, int nblk0,
        const float* __restrict__ W1, float* __restrict__ P1, int N1, int ks1, int nbx1)
{
    __shared__ unsigned short Ah[2*2048], Al[2*2048], Bh[2*2048], Bl[2*2048];
    int bid = blockIdx.x;
    if (bid < nblk0){
        gemm_core_raw(Araw, KA, W0, P0, N0, ks0, bid%nbx0, bid/nbx0, Ah, Al, Bh, Bl);
    } else {
        bid -= nblk0;
        gemm_core_raw(Araw, KA, W1, P1, N1, ks1, bid%nbx1, bid/nbx1, Ah, Al, Bh, Bl);
    }
}

// ================= norms =================
static __device__ __forceinline__ void rms_core(const float* __restrict__ P,
        const float* __restrict__ w, unsigned short* __restrict__ Hi,
        unsigned short* __restrict__ Lo, int S, int b, float* red)
{
    const int t = threadIdx.x;
    float v[6]; float ss = 0.f;
#pragma unroll
    for (int j=0;j<6;++j){
        int n = j*256 + t;
        float s = 0.f;
        for (int sp=0; sp<S; ++sp) s += P[((size_t)sp*64+b)*1536 + n];
        v[j] = s; ss += s*s;
    }
#pragma unroll
    for (int off=32; off>=1; off>>=1) ss += __shfl_xor(ss, off, 64);
    if ((t&63)==0) red[t>>6] = ss;
    __syncthreads();
    float tot = red[0]+red[1]+red[2]+red[3];
    float rs = rsqrtf(tot/1536.f + 1e-6f);
#pragma unroll
    for (int j=0;j<6;++j){
        int n = j*256+t;
        float val = v[j]*rs*w[n];
        unsigned short hs = f2bf(val);
        unsigned short ls = f2bf(val - bf2f(hs));
        size_t ui = (size_t)(n>>3)*512 + b*8 + (n&7);
        Hi[ui] = hs; Lo[ui] = ls;
    }
}

static __device__ __forceinline__ void kvrope_core(const float* __restrict__ P,
        const float* __restrict__ w, const float* __restrict__ cosb, const float* __restrict__ sinb,
        float* __restrict__ latent, int S, int b, float* vals, float* red)
{
    const int t = threadIdx.x;
    float ss = 0.f;
    for (int j=0;j<3;++j){
        int n = j*256+t;
        if (n < 576){
            float s=0.f;
            for (int sp=0;sp<S;++sp) s += P[((size_t)sp*64+b)*576 + n];
            vals[n]=s;
            if (n<512) ss += s*s;
        }
    }
#pragma unroll
    for (int off=32; off>=1; off>>=1) ss += __shfl_xor(ss, off, 64);
    if ((t&63)==0) red[t>>6]=ss;
    __syncthreads();
    float tot = red[0]+red[1]+red[2]+red[3];
    float rs = rsqrtf(tot/512.f + 1e-6f);
    for (int j=0;j<3;++j){
        int n = j*256+t;
        if (n<576){
            float o;
            if (n < 512) o = vals[n]*rs*w[n];
            else if (n < 544){ int i=n-512; o = vals[512+2*i]*cosb[b*32+i] - vals[513+2*i]*sinb[b*32+i]; }
            else            { int i=n-544; o = vals[513+2*i]*cosb[b*32+i] + vals[512+2*i]*sinb[b*32+i]; }
            latent[(size_t)b*576 + n] = o;
        }
    }
}

__global__ __launch_bounds__(256) void norm_dual(
        const float* __restrict__ Pq, const float* __restrict__ qw,
        unsigned short* __restrict__ Hi, unsigned short* __restrict__ Lo, int Sq,
        const float* __restrict__ Pkv, const float* __restrict__ kvw,
        const float* __restrict__ cosb, const float* __restrict__ sinb,
        float* __restrict__ latent, int Skv)
{
    __shared__ float vals[576];
    __shared__ float red[4];
    if (blockIdx.x < 64) rms_core(Pq, qw, Hi, Lo, Sq, blockIdx.x, red);
    else                 kvrope_core(Pkv, kvw, cosb, sinb, latent, Skv, blockIdx.x-64, vals, red);
}

// ---------- finish q: reduce partials; nope part -> packed hi/lo A (per-h frag layout);
// rope part -> query[512..]
__global__ __launch_bounds__(256) void finish_q(const float* __restrict__ P,
        const float* __restrict__ cosb, const float* __restrict__ sinb,
        unsigned short* __restrict__ qh, unsigned short* __restrict__ ql,
        float* __restrict__ query, int S)
{
    int i = blockIdx.x*256 + threadIdx.x;
    int b = i / 6144, n = i - b*6144;
    float s = 0.f;
    for (int sp=0; sp<S; ++sp) s += P[((size_t)sp*64+b)*6144 + n];
    int h = n/192, nl = n - h*192;
    if (nl < 128){
        unsigned short hs = f2bf(s);
        unsigned short ls = f2bf(s - bf2f(hs));
        size_t ui = (size_t)h*8192 + (size_t)(nl>>3)*512 + b*8 + (nl&7);
        qh[ui]=hs; ql[ui]=ls;
    } else {
        int i2 = (nl-128)>>1;
        float other = __shfl_xor(s, 1);
        float c = cosb[b*32+i2], sn = sinb[b*32+i2];
        float* o = query + ((size_t)b*32+h)*576;
        if ((nl&1)==0) o[512+i2] = s*c - other*sn;
        else           o[544+i2] = s*c + other*sn;
    }
}

// ---------- ql_nope via MFMA, packed A
__global__ __launch_bounds__(256) void qlnope_mfma(const unsigned short* __restrict__ qh,
        const unsigned short* __restrict__ ql,
        const float* __restrict__ wukt, float* __restrict__ query)
{
    __shared__ unsigned short Bh[4096], Bl[4096];
    const int h = blockIdx.x, r0 = blockIdx.y*128;
    const int tid = threadIdx.x;
    const int w = tid>>6, l = tid&63, lm = l&15, lg = l>>4;
    f32x4 acc[8];
#pragma unroll
    for (int i=0;i<8;++i){ acc[i][0]=0.f; acc[i][1]=0.f; acc[i][2]=0.f; acc[i][3]=0.f; }

    for (int ck=0; ck<4; ++ck){
        const int k0 = ck*32;
        unsigned short hh[2][8], ll[2][8]; int wid0 = tid*2;
#pragma unroll
        for (int wi=0; wi<2; ++wi){
            int wid = wid0 + wi;
            int ntile = wid>>6, kg = (wid>>4)&3, nl = wid&15;
            int n = r0 + ntile*16 + nl;
            const float* wp = wukt + (size_t)h*65536 + (size_t)(k0+kg*8)*512 + n;
#pragma unroll
            for (int j=0;j<8;++j){
                float v = wp[(size_t)j*512];
                hh[wi][j] = f2bf(v);
                ll[wi][j] = f2bf(v - bf2f(hh[wi][j]));
            }
        }
        __syncthreads();
#pragma unroll
        for (int wi=0; wi<2; ++wi){
            int wid = wid0 + wi;
            uint4 uh, ul;
            uh.x=(unsigned)hh[wi][0]|((unsigned)hh[wi][1]<<16); uh.y=(unsigned)hh[wi][2]|((unsigned)hh[wi][3]<<16);
            uh.z=(unsigned)hh[wi][4]|((unsigned)hh[wi][5]<<16); uh.w=(unsigned)hh[wi][6]|((unsigned)hh[wi][7]<<16);
            ul.x=(unsigned)ll[wi][0]|((unsigned)ll[wi][1]<<16); ul.y=(unsigned)ll[wi][2]|((unsigned)ll[wi][3]<<16);
            ul.z=(unsigned)ll[wi][4]|((unsigned)ll[wi][5]<<16); ul.w=(unsigned)ll[wi][6]|((unsigned)ll[wi][7]<<16);
            *(uint4*)(Bh + wid*8) = uh;
            *(uint4*)(Bl + wid*8) = ul;
        }
        __syncthreads();
        size_t ai = (size_t)h*8192 + (size_t)(ck*4+lg)*512 + (size_t)(w*16+lm)*8;
        union{uint4 u; bf16x8 v;} fh, fl;
        fh.u = *(const uint4*)(qh + ai);
        fl.u = *(const uint4*)(ql + ai);
#pragma unroll
        for (int nt=0;nt<8;++nt){
            const int fb = (nt*64 + lg*16 + lm)*8;
            bf16x8 fbh = *(const bf16x8*)(Bh + fb);
            bf16x8 fbl = *(const bf16x8*)(Bl + fb);
            acc[nt] = __builtin_amdgcn_mfma_f32_16x16x32_bf16(fh.v, fbh, acc[nt], 0,0,0);
            acc[nt] = __builtin_amdgcn_mfma_f32_16x16x32_bf16(fl.v, fbh, acc[nt], 0,0,0);
            acc[nt] = __builtin_amdgcn_mfma_f32_16x16x32_bf16(fh.v, fbl, acc[nt], 0,0,0);
        }
        __syncthreads();
    }
#pragma unroll
    for (int nt=0;nt<8;++nt){
        int r = r0 + nt*16 + lm;
#pragma unroll
        for (int qq=0;qq<4;++qq){
            int bb = w*16 + lg*4 + qq;
            query[((size_t)bb*32 + h)*576 + r] = acc[nt][qq];
        }
    }
}

// Vt flat layout: addr_u16(d,key) = (d>>2)*64 + ((d&3)^((d>>3)&3))*16 + key
static __device__ __forceinline__ int vt_addr(int d, int key){
    return (d>>2)*64 + (((d&3)^((d>>3)&3))<<4) + key;
}

// ---------- flash decode attention v8: 512 thr, triple-buffer DMA, counted vmcnt,
// QK = 8 d-group waves x dual-ht MFMA (K converted once per chunk)
__global__ __launch_bounds__(512,1) void attn_mfma(const float* __restrict__ query,
        const float* __restrict__ kv, const float* __restrict__ latent,
        const int* __restrict__ slots, const int* __restrict__ seq_lens,
        float* __restrict__ Opart, float* __restrict__ Mpart, float* __restrict__ Lpart)
{
    __shared__ float Kf[3][16*576];               // 110592 B
    __shared__ unsigned short Vt[8192];           // 16384 B
    __shared__ float S_s[8][32][16];              // 16384 B
    __shared__ unsigned short P_s[32][40];        // 2560 B (cols 16..31 zero)
    __shared__ float alpha_s[32];                 // 128 B  -> total 146048 B

    const int b = blockIdx.y, sp = blockIdx.x;
    const int tid = threadIdx.x;
    const int w = tid>>6, l = tid&63;
    const int lm = l&15, lg = l>>4;
    const int ht = w&1;                  // PV h-tile
    const int dg = w>>1;                 // PV r-quarter
    // QK d-group: chunk starts {0,3,5,7,9,12,14,16}, counts {3,2,2,2,3,2,2,2}
    const int cs = 2*w + (w>=1?1:0) + (w>=5?1:0);
    const int cnt = ((w&3)==0)?3:2;
    const int seqlen = seq_lens[b];
    const int slot = slots[b];
    const int k0 = sp*KSPAN;
    const int myh = tid>>4, s5 = tid&15; // softmax: 16 threads/head, 1 key each

    P_s[tid>>4][16 + (tid&15)] = 0;

    // Q fragments: both h-tiles for this wave's chunk range
    bf16x8 qf[2][3];
#pragma unroll
    for (int h2=0; h2<2; ++h2){
        const float* qrow = query + ((size_t)b*32 + h2*16 + lm)*576;
#pragma unroll
        for (int ss=0;ss<3;++ss){
            union{uint4 u; bf16x8 v;} cv;
            if (ss < cnt){
                int d0 = (cs+ss)*32 + lg*8;
                float4 a = *(const float4*)(qrow + d0);
                float4 c = *(const float4*)(qrow + d0 + 4);
                cv.u.x=pack2(a.x,a.y); cv.u.y=pack2(a.z,a.w);
                cv.u.z=pack2(c.x,c.y); cv.u.w=pack2(c.z,c.w);
            } else {
                cv.u.x=0; cv.u.y=0; cv.u.z=0; cv.u.w=0;
            }
            qf[h2][ss]=cv.v;
        }
    }

    // DMA stage: 36 glds16/tile, slot s -> wave s&7
    auto issue_tile = [&](int tt, int buf){
        const int gkb = k0 + tt*TK;
#pragma unroll
        for (int i=0;i<5;++i){
            int s = i*8 + w;
            if (s < 36){
                int B = s*1024 + l*16;
                int r = B / 2304;
                int gs = (B - r*2304) >> 4;
                int g  = gs ^ (r&7);
                int gk = gkb + r; if (gk > KCTX-1) gk = KCTX-1;
                const float* src = (gk==slot) ? (latent + (size_t)b*576 + g*4)
                                              : (kv + ((size_t)b*KCTX + gk)*576 + g*4);
                glds16(src, ((char*)&Kf[buf][0]) + B);
            }
        }
    };

    f32x4 oacc[8];
#pragma unroll
    for (int i=0;i<8;++i){ oacc[i][0]=0.f; oacc[i][1]=0.f; oacc[i][2]=0.f; oacc[i][3]=0.f; }
    float m_run = NEGINF, l_run = 0.f;

    issue_tile(0, 0);
    issue_tile(1, 1);
    if (w < 4) { asm volatile("s_waitcnt vmcnt(5)" ::: "memory"); }
    else       { asm volatile("s_waitcnt vmcnt(4)" ::: "memory"); }
    __builtin_amdgcn_s_barrier();

    int cur = 0;
    for (int tt=0; tt<NTILE; ++tt){
        if (tt+2 < NTILE){
            int ib = cur+2; if (ib>=3) ib-=3;
            issue_tile(tt+2, ib);
        }

        // ---- transpose Kf[cur] (d<512) -> Vt bf16
        {
            const int kg = tid&1;
            const int dq = (tid>>1)&127;
            const int rep = tid>>8;
            float4 rv[4];
#pragma unroll
            for (int i=0;i<4;++i){
                int r = kg*8 + rep*4 + i;
                rv[i] = *(const float4*)(&Kf[cur][r*576 + ((dq ^ (r&7))<<2)]);
            }
#pragma unroll
            for (int j=0;j<4;++j){
                uint2 o;
                o.x = pack2(((const float*)&rv[0])[j], ((const float*)&rv[1])[j]);
                o.y = pack2(((const float*)&rv[2])[j], ((const float*)&rv[3])[j]);
                *(uint2*)(Vt + vt_addr(dq*4+j, kg*8) + rep*4) = o;
            }
        }
        // ---- QK^T partial: this wave's chunks, K converted ONCE, two MFMAs share B
        {
            f32x4 s0, s1;
            s0[0]=0.f; s0[1]=0.f; s0[2]=0.f; s0[3]=0.f;
            s1[0]=0.f; s1[1]=0.f; s1[2]=0.f; s1[3]=0.f;
            const float* kb = &Kf[cur][lm*576];
            const int sw = lm&7;
            __builtin_amdgcn_s_setprio(1);
#pragma unroll
            for (int ss=0;ss<3;++ss){
                if (ss < cnt){          // wave-uniform bound
                    int g = (cs+ss)*8 + lg*2;
                    float4 fa = *(const float4*)(kb + ((g ^ sw)<<2));
                    float4 fb = *(const float4*)(kb + (((g+1) ^ sw)<<2));
                    union{uint4 u; bf16x8 v;} cv;
                    cv.u.x = pack2(fa.x, fa.y); cv.u.y = pack2(fa.z, fa.w);
                    cv.u.z = pack2(fb.x, fb.y); cv.u.w = pack2(fb.z, fb.w);
                    s0 = __builtin_amdgcn_mfma_f32_16x16x32_bf16(qf[0][ss], cv.v, s0, 0,0,0);
                    s1 = __builtin_amdgcn_mfma_f32_16x16x32_bf16(qf[1][ss], cv.v, s1, 0,0,0);
                }
            }
            __builtin_amdgcn_s_setprio(0);
#pragma unroll
            for (int r=0;r<4;++r){
                S_s[w][(lg<<2)+r][lm]      = s0[r];
                S_s[w][16+(lg<<2)+r][lm]   = s1[r];
            }
        }
        LGKM_BARRIER();                    // #1 (vmcnt NOT drained)

        // ---- online softmax: 16 threads/head, 1 key each; sum 8 wave-partials
        {
            const int kbase = k0 + tt*TK;
            float v = 0.f;
#pragma unroll
            for (int i=0;i<8;++i) v += S_s[i][myh][s5];
            v *= SM_SCALE;
            float sc = (kbase + s5 < seqlen) ? v : NEGINF;
            float tmax = sc;
            tmax = fmaxf(tmax, __shfl_xor(tmax,1));
            tmax = fmaxf(tmax, __shfl_xor(tmax,2));
            tmax = fmaxf(tmax, __shfl_xor(tmax,4));
            tmax = fmaxf(tmax, __shfl_xor(tmax,8));
            float mnew = fmaxf(m_run, tmax);
            float al = __expf(m_run - mnew);
            float pv = (sc > 0.5f*NEGINF) ? __expf(sc-mnew) : 0.f;
            P_s[myh][s5] = f2bf(pv);
            float ps = pv;
            ps += __shfl_xor(ps,1); ps += __shfl_xor(ps,2);
            ps += __shfl_xor(ps,4); ps += __shfl_xor(ps,8);
            l_run = l_run*al + ps;
            m_run = mnew;
            if (s5==0) alpha_s[myh] = al;
        }
        LGKM_BARRIER();                    // #2

        // ---- PV
        {
            float al4[4];
#pragma unroll
            for (int r=0;r<4;++r) al4[r] = alpha_s[ht*16 + (lg<<2) + r];
            bf16x8 pa = *(const bf16x8*)(&P_s[ht*16+lm][lg*8]);
            __builtin_amdgcn_s_setprio(1);
#pragma unroll
            for (int nt=0;nt<8;++nt){
                f32x4 o = oacc[nt];
                o[0]*=al4[0]; o[1]*=al4[1]; o[2]*=al4[2]; o[3]*=al4[3];
                int r = dg*128 + nt*16 + lm;
                bf16x8 bv = *(const bf16x8*)(Vt + vt_addr(r, (lg&1)*8));
                oacc[nt] = __builtin_amdgcn_mfma_f32_16x16x32_bf16(pa, bv, o, 0,0,0);
            }
            __builtin_amdgcn_s_setprio(0);
        }
        // ---- tail: counted wait on next tile's DMA (tile t+2 stays in flight)
        if (tt+2 < NTILE){
            if (w < 4) { asm volatile("s_waitcnt vmcnt(5)" ::: "memory"); }
            else       { asm volatile("s_waitcnt vmcnt(4)" ::: "memory"); }
            __builtin_amdgcn_s_barrier();
        } else if (tt+1 < NTILE){
            asm volatile("s_waitcnt vmcnt(0)" ::: "memory");
            __builtin_amdgcn_s_barrier();
        }
        cur = cur+1; if (cur>=3) cur-=3;
    }

    const int obase = (b*NSPLIT+sp)*32;
#pragma unroll
    for (int nt=0;nt<8;++nt){
        int r = dg*128 + nt*16 + lm;
#pragma unroll
        for (int qq=0;qq<4;++qq){
            int h = ht*16 + (lg<<2) + qq;
            Opart[((size_t)(obase+h))*512 + r] = oacc[nt][qq];
        }
    }
    if (s5==0){ Mpart[obase+myh]=m_run; Lpart[obase+myh]=l_run; }
}

// ---------- av_uv via MFMA with fused split-merge + fused hi/lo pack of ao
__global__ __launch_bounds__(256) void av_uv_merge(const float* __restrict__ Opart,
        const float* __restrict__ Mpart, const float* __restrict__ Lpart,
        const float* __restrict__ wuv,
        unsigned short* __restrict__ Hi, unsigned short* __restrict__ Lo)
{
    __shared__ unsigned short Bh[4096], Bl[4096];
    __shared__ unsigned short Ah[512], Al[512];
    __shared__ float lwn[16][4];
    const int h = blockIdx.x, bg = blockIdx.y;
    const int tid = threadIdx.x;
    const int w = tid>>6, l = tid&63, lm = l&15, lg = l>>4;

    if (tid < 16){
        int b = bg*16 + tid;
        float m0 = Mpart[(b*NSPLIT+0)*32+h], m1 = Mpart[(b*NSPLIT+1)*32+h];
        float m2 = Mpart[(b*NSPLIT+2)*32+h], m3 = Mpart[(b*NSPLIT+3)*32+h];
        float M = fmaxf(fmaxf(m0,m1),fmaxf(m2,m3));
        float w0 = __expf(m0-M), w1 = __expf(m1-M), w2 = __expf(m2-M), w3 = __expf(m3-M);
        float L = w0*Lpart[(b*NSPLIT+0)*32+h] + w1*Lpart[(b*NSPLIT+1)*32+h]
                + w2*Lpart[(b*NSPLIT+2)*32+h] + w3*Lpart[(b*NSPLIT+3)*32+h];
        float inv = 1.f/L;
        lwn[tid][0]=w0*inv; lwn[tid][1]=w1*inv; lwn[tid][2]=w2*inv; lwn[tid][3]=w3*inv;
    }
    __syncthreads();

    f32x4 acc[2];
#pragma unroll
    for (int i=0;i<2;++i){ acc[i][0]=0.f; acc[i][1]=0.f; acc[i][2]=0.f; acc[i][3]=0.f; }

    for (int ck=0; ck<16; ++ck){
        const int k0 = ck*32;
        unsigned short hh[2][8], ll[2][8]; int wid0 = tid*2;
#pragma unroll
        for (int wi=0; wi<2; ++wi){
            int wid = wid0 + wi;
            int ntile = wid>>6, kg = (wid>>4)&3, nl = wid&15;
            int n = ntile*16 + nl;
            const float* wp = wuv + (size_t)h*65536 + (size_t)(k0+kg*8)*128 + n;
#pragma unroll
            for (int j=0;j<8;++j){
                float v = wp[(size_t)j*128];
                hh[wi][j] = f2bf(v);
                ll[wi][j] = f2bf(v - bf2f(hh[wi][j]));
            }
        }
        float av[2];
#pragma unroll
        for (int e=0;e<2;++e){
            int id = tid*2+e;
            int row = id>>5, k = id&31;
            int bb = bg*16 + row;
            const float* op = Opart + (((size_t)bb*NSPLIT)*32 + h)*512 + k0 + k;
            av[e] = lwn[row][0]*op[0] + lwn[row][1]*op[16384]
                  + lwn[row][2]*op[32768] + lwn[row][3]*op[49152];
        }
        __syncthreads();
#pragma unroll
        for (int wi=0; wi<2; ++wi){
            int wid = wid0 + wi;
            uint4 uh, ul;
            uh.x=(unsigned)hh[wi][0]|((unsigned)hh[wi][1]<<16); uh.y=(unsigned)hh[wi][2]|((unsigned)hh[wi][3]<<16);
            uh.z=(unsigned)hh[wi][4]|((unsigned)hh[wi][5]<<16); uh.w=(unsigned)hh[wi][6]|((unsigned)hh[wi][7]<<16);
            ul.x=(unsigned)ll[wi][0]|((unsigned)ll[wi][1]<<16); ul.y=(unsigned)ll[wi][2]|((unsigned)ll[wi][3]<<16);
            ul.z=(unsigned)ll[wi][4]|((unsigned)ll[wi][5]<<16); ul.w=(unsigned)ll[wi][6]|((unsigned)ll[wi][7]<<16);
            *(uint4*)(Bh + wid*8) = uh;
            *(uint4*)(Bl + wid*8) = ul;
        }
#pragma unroll
        for (int e=0;e<2;++e){
            int id = tid*2+e;
            int row = id>>5, k = id&31;
            unsigned short hs = f2bf(av[e]);
            unsigned short ls = f2bf(av[e] - bf2f(hs));
            int ai = ((k>>3)*16 + row)*8 + (k&7);
            Ah[ai] = hs; Al[ai] = ls;
        }
        __syncthreads();
        const int fa = (lg*16 + lm)*8;
        bf16x8 fah = *(const bf16x8*)(Ah + fa);
        bf16x8 fal = *(const bf16x8*)(Al + fa);
#pragma unroll
        for (int i=0;i<2;++i){
            int nt = w*2 + i;
            const int fb = (nt*64 + lg*16 + lm)*8;
            bf16x8 fbh = *(const bf16x8*)(Bh + fb);
            bf16x8 fbl = *(const bf16x8*)(Bl + fb);
            acc[i] = __builtin_amdgcn_mfma_f32_16x16x32_bf16(fah, fbh, acc[i], 0,0,0);
            acc[i] = __builtin_amdgcn_mfma_f32_16x16x32_bf16(fal, fbh, acc[i], 0,0,0);
            acc[i] = __builtin_amdgcn_mfma_f32_16x16x32_bf16(fah, fbl, acc[i], 0,0,0);
        }
        __syncthreads();
    }
#pragma unroll
    for (int i=0;i<2;++i){
        int nt = w*2 + i;
#pragma unroll
        for (int qq=0;qq<4;++qq){
            float val = acc[i][qq];
            int bb = bg*16 + lg*4 + qq;
            int k = h*128 + nt*16 + lm;
            unsigned short hv = f2bf(val);
            unsigned short lv = f2bf(val - bf2f(hv));
            size_t ui = (size_t)(k>>3)*512 + bb*8 + (k&7);
            Hi[ui] = hv; Lo[ui] = lv;
        }
    }
}

extern "C" void kernel_launch(void* const* d_in, const int* in_sizes, int n_in,
                              void* d_out, int out_size, void* d_ws, size_t ws_size,
                              hipStream_t stream)
{
    const float* hidden = (const float*)d_in[0];
    const float* cosb   = (const float*)d_in[1];
    const float* sinb   = (const float*)d_in[2];
    const float* kv     = (const float*)d_in[3];
    const float* w_q_a  = (const float*)d_in[4];
    const float* q_ln   = (const float*)d_in[5];
    const float* w_q_b  = (const float*)d_in[6];
    const float* w_kv_a = (const float*)d_in[7];
    const float* kv_ln  = (const float*)d_in[8];
    const float* w_uk_t = (const float*)d_in[9];
    const float* w_uv   = (const float*)d_in[10];
    const float* w_o    = (const float*)d_in[11];
    const int* slots    = (const int*)d_in[12];
    const int* seqlens  = (const int*)d_in[13];
    float* out = (float*)d_out;

    float* W = (float*)d_ws;
    float* P0     = W;                   // 4,194,304 f32 (wqa/wqb partials, attn Opart)
    float* P1     = W + 4194304;         // 2,097,152 (wkva partials)
    float* query  = W + 6291456;         // 1,179,648
    float* latent = W + 7471104;         // 36,864
    float* Mp     = W + 7507968;         // 8,192
    float* Lp     = W + 7516160;         // 8,192
    unsigned short* pkq_h  = (unsigned short*)(W + 7524352);   // 262,144 u16 = 131,072 f32
    unsigned short* pkq_l  = (unsigned short*)(W + 7655424);
    unsigned short* pkqc_h = (unsigned short*)(W + 7786496);   // 98,304 u16 = 49,152 f32
    unsigned short* pkqc_l = (unsigned short*)(W + 7835648);
    unsigned short* pkao_h = (unsigned short*)(W + 7884800);   // 262,144 u16 = 131,072 f32
    unsigned short* pkao_l = (unsigned short*)(W + 8015872);   // end 8,146,944

    // zero output for atomic accumulation (w_o GEMM)
    hipMemsetAsync(out, 0, (size_t)NB*HID*sizeof(float), stream);

    // hidden @ w_q_a (24x28) || hidden @ w_kv_a (9x56), A converted in-reg
    hipLaunchKernelGGL(gemm_dual_raw, dim3(672+504), dim3(256), 0, stream,
                       hidden, HID, w_q_a, P0, 1536, 8, 24, 672, w_kv_a, P1, 576, 4, 9);
    hipLaunchKernelGGL(norm_dual, dim3(128), dim3(256), 0, stream,
                       P0, q_ln, pkqc_h, pkqc_l, 28, P1, kv_ln, cosb, sinb, latent, 56);
    hipLaunchKernelGGL(gemm_mfma, dim3(96,6), dim3(256), 0, stream, pkqc_h, pkqc_l, w_q_b, P0, 6144, 8);
    hipLaunchKernelGGL(finish_q, dim3(1536), dim3(256), 0, stream, P0, cosb, sinb, pkq_h, pkq_l, query, 6);
    hipLaunchKernelGGL(qlnope_mfma, dim3(32,4), dim3(256), 0, stream, pkq_h, pkq_l, w_uk_t, query);
    hipLaunchKernelGGL(attn_mfma, dim3(NSPLIT,64), dim3(512), 0, stream,
                       query, kv, latent, slots, seqlens, P0, Mp, Lp);
    hipLaunchKernelGGL(av_uv_merge, dim3(32,4), dim3(256), 0, stream, P0, Mp, Lp, w_uv, pkao_h, pkao_l);
    hipLaunchKernelGGL(gemm_atomic, dim3(112,8), dim3(256), 0, stream, pkao_h, pkao_l, w_o, out, 7168, 16);
}